// Round 5
// baseline (178.489 us; speedup 1.0000x reference)
//
#include <hip/hip_runtime.h>

#define DD 128
#define CAP 32
#define SPILL_MAX 4096

typedef __attribute__((ext_vector_type(8))) short short8;
typedef __attribute__((ext_vector_type(4))) float float4v;

static __device__ __forceinline__ unsigned short f2bf(float x) {
    unsigned u = __builtin_bit_cast(unsigned, x);
    u += 0x7fffu + ((u >> 16) & 1u);   // RNE
    return (unsigned short)(u >> 16);
}
static __device__ __forceinline__ float bflo(unsigned u) {
    return __builtin_bit_cast(float, u << 16);
}
static __device__ __forceinline__ float bfhi(unsigned u) {
    return __builtin_bit_cast(float, u & 0xffff0000u);
}

// ---- fused init: [0,128) emb@W1 bf16 table; [128,136) W2 swizzle; [136,136+Hb) edge bucketing ----
// bucket segment: 2 edges/thread for ~17 waves/CU of atomic-latency hiding
__global__ __launch_bounds__(256) void k_init(const float* __restrict__ emb,
                                              const float* __restrict__ W1,
                                              const float* __restrict__ W2,
                                              unsigned* __restrict__ embW1b,
                                              unsigned short* __restrict__ Wb,
                                              const int* __restrict__ src,
                                              const int* __restrict__ dst,
                                              const int* __restrict__ node_ids,
                                              int* __restrict__ cursor,
                                              unsigned* __restrict__ recs,
                                              int* __restrict__ spillCnt,
                                              int* __restrict__ spill_d,
                                              int* __restrict__ spill_r, int E) {
    int blk = blockIdx.x;
    if (blk < 128) {
        int w = threadIdx.x >> 6;
        int t = threadIdx.x & 63;
        int p = blk * 4 + w;
        int c0 = t * 2, c1 = t * 2 + 1;
        float s0 = 0.f, s1 = 0.f;
#pragma unroll 8
        for (int k = 0; k < DD; k++) {
            float e = emb[p * DD + k];
            s0 += e * W1[k * DD + c0];
            s1 += e * W1[k * DD + c1];
        }
        embW1b[p * 64 + t] = (unsigned)f2bf(s0) | ((unsigned)f2bf(s1) << 16);
    } else if (blk < 136) {
        int t = (blk - 128) * 256 + threadIdx.x;   // 0..2047: (nt, ks, lane)
        int nt = t >> 8, ks = (t >> 6) & 3, lane = t & 63;
        int n = nt * 16 + (lane & 15);
        int kbase = ks * 32 + (lane >> 4) * 8;
        unsigned short* o = Wb + (size_t)t * 8;
#pragma unroll
        for (int j = 0; j < 8; j++)
            o[j] = f2bf(W2[(kbase + j) * DD + n]);
    } else {
        int base = ((blk - 136) * 256 + threadIdx.x) * 2;
        if (base >= E) return;
#pragma unroll
        for (int u = 0; u < 2; u++) {
            int e = base + u;
            if (e >= E) break;
            int s = src[e], d = dst[e];
            unsigned rec = (unsigned)s | ((unsigned)node_ids[s] << 16);
            int pos = atomicAdd(&cursor[d], 1);
            if (pos < CAP) {
                recs[(size_t)d * CAP + pos] = rec;
            } else {
                int sp = atomicAdd(spillCnt, 1);
                if (sp < SPILL_MAX) { spill_d[sp] = d; spill_r[sp] = (int)rec; }
            }
        }
    }
}

// ---- layer 1: aggregation (depth-8 pipelined loads) + LN -> x1b (bf16) + disf ----
__global__ __launch_bounds__(256) void k_node1(const int* __restrict__ cursor,
                                               const unsigned* __restrict__ recs,
                                               const int* __restrict__ node_ids,
                                               const float* __restrict__ emb,
                                               const unsigned* __restrict__ embW1b,
                                               const int* __restrict__ spillCnt,
                                               const int* __restrict__ spill_d,
                                               const int* __restrict__ spill_r,
                                               const float* __restrict__ b1,
                                               const float* __restrict__ g1,
                                               const float* __restrict__ beta1,
                                               unsigned* __restrict__ x1b,
                                               float* __restrict__ disf, int N) {
    int gid = blockIdx.x * blockDim.x + threadIdx.x;
    int wave = gid >> 6;
    int lane = threadIdx.x & 63;
    int qtr = lane >> 4;
    int l = lane & 15;
    int qbase = lane & 48;
    int i = wave * 4 + qtr;
    if (i >= N) return;
    int c = l * 8;
    // ---- issue self-row loads early so they overlap the edge-gather loop ----
    int dg = cursor[i];
    unsigned rv0 = recs[(size_t)i * CAP + l];
    unsigned rv1 = recs[(size_t)i * CAP + 16 + l];
    int pid = node_ids[i];
    float4 ev0 = *(const float4*)(emb + (size_t)pid * DD + c);
    float4 ev1 = *(const float4*)(emb + (size_t)pid * DD + c + 4);
    uint4 hw = *(const uint4*)(embW1b + pid * 64 + l * 4);
    int dgc = (dg < CAP) ? dg : CAP;
    float a0 = 0.f, a1 = 0.f, a2 = 0.f, a3 = 0.f, a4 = 0.f, a5 = 0.f, a6 = 0.f, a7 = 0.f;
    for (int j0 = 0; j0 < dgc; j0 += 8) {
        unsigned rvs = (j0 < 16) ? rv0 : rv1;
        uint4 buf[8]; int cb[8]; float nn[8];
#pragma unroll
        for (int q = 0; q < 8; q++) {
            int e = j0 + q;
            int ec = (e < dgc) ? e : (dgc - 1);
            unsigned rec = __shfl(rvs, qbase + (ec & 15), 64);
            nn[q] = (e < dgc) ? 1.f : 0.f;
            buf[q] = *(const uint4*)(embW1b + ((rec >> 16) & 511u) * 64 + l * 4);
            cb[q] = cursor[rec & 0xFFFFu];
        }
#pragma unroll
        for (int q = 0; q < 8; q++) {
            float n = rsqrtf((float)cb[q] + 1.f) * nn[q];
            uint4 a = buf[q];
            a0 += bflo(a.x) * n; a1 += bfhi(a.x) * n;
            a2 += bflo(a.y) * n; a3 += bfhi(a.y) * n;
            a4 += bflo(a.z) * n; a5 += bfhi(a.z) * n;
            a6 += bflo(a.w) * n; a7 += bfhi(a.w) * n;
        }
    }
    if (dg > CAP) {   // rare spill path
        int sc = *spillCnt; if (sc > SPILL_MAX) sc = SPILL_MAX;
        for (int j = 0; j < sc; j++) {
            if (spill_d[j] == i) {
                unsigned rec = (unsigned)spill_r[j];
                int s = rec & 0xFFFFu;
                float n = rsqrtf((float)cursor[s] + 1.0f);
                uint4 a = *(const uint4*)(embW1b + ((rec >> 16) & 511u) * 64 + l * 4);
                a0 += bflo(a.x) * n; a1 += bfhi(a.x) * n;
                a2 += bflo(a.y) * n; a3 += bfhi(a.y) * n;
                a4 += bflo(a.z) * n; a5 += bfhi(a.z) * n;
                a6 += bflo(a.w) * n; a7 += bfhi(a.w) * n;
            }
        }
    }
    float di = rsqrtf((float)dg + 1.0f);
    float4 bb0 = *(const float4*)(b1 + c);
    float4 bb1 = *(const float4*)(b1 + c + 4);
    float v0 = ev0.x + di * (a0 + di * bflo(hw.x)) + bb0.x;
    float v1 = ev0.y + di * (a1 + di * bfhi(hw.x)) + bb0.y;
    float v2 = ev0.z + di * (a2 + di * bflo(hw.y)) + bb0.z;
    float v3 = ev0.w + di * (a3 + di * bfhi(hw.y)) + bb0.w;
    float v4 = ev1.x + di * (a4 + di * bflo(hw.z)) + bb1.x;
    float v5 = ev1.y + di * (a5 + di * bfhi(hw.z)) + bb1.y;
    float v6 = ev1.z + di * (a6 + di * bflo(hw.w)) + bb1.z;
    float v7 = ev1.w + di * (a7 + di * bfhi(hw.w)) + bb1.w;
    float sum = v0 + v1 + v2 + v3 + v4 + v5 + v6 + v7;
#pragma unroll
    for (int o = 8; o >= 1; o >>= 1) sum += __shfl_xor(sum, o, 64);
    float mu = sum * (1.f / DD);
    float d0 = v0 - mu, d1 = v1 - mu, d2 = v2 - mu, d3 = v3 - mu;
    float d4 = v4 - mu, d5 = v5 - mu, d6 = v6 - mu, d7 = v7 - mu;
    float ss = d0 * d0 + d1 * d1 + d2 * d2 + d3 * d3 + d4 * d4 + d5 * d5 + d6 * d6 + d7 * d7;
#pragma unroll
    for (int o = 8; o >= 1; o >>= 1) ss += __shfl_xor(ss, o, 64);
    float r = rsqrtf(ss * (1.f / DD) + 1e-5f);
    float4 gg0 = *(const float4*)(g1 + c);
    float4 gg1 = *(const float4*)(g1 + c + 4);
    float4 be0 = *(const float4*)(beta1 + c);
    float4 be1 = *(const float4*)(beta1 + c + 4);
    float o0 = d0 * r * gg0.x + be0.x;
    float o1 = d1 * r * gg0.y + be0.y;
    float o2 = d2 * r * gg0.z + be0.z;
    float o3 = d3 * r * gg0.w + be0.w;
    float o4 = d4 * r * gg1.x + be1.x;
    float o5 = d5 * r * gg1.y + be1.y;
    float o6 = d6 * r * gg1.z + be1.z;
    float o7 = d7 * r * gg1.w + be1.w;
    uint4 pk;
    pk.x = (unsigned)f2bf(o0) | ((unsigned)f2bf(o1) << 16);
    pk.y = (unsigned)f2bf(o2) | ((unsigned)f2bf(o3) << 16);
    pk.z = (unsigned)f2bf(o4) | ((unsigned)f2bf(o5) << 16);
    pk.w = (unsigned)f2bf(o6) | ((unsigned)f2bf(o7) << 16);
    *(uint4*)(x1b + (size_t)i * 64 + l * 4) = pk;
    if (l == 0) disf[i] = di;
}

// ---- layer 2: each WAVE owns 16 nodes. All 4 row-groups' setup loads (recs row,
//      disf, x1 self-row, deg) are prefetched upfront to collapse the per-group
//      dependent-load bubble; gathers stay depth-8 pipelined. Then per-wave MFMA
//      z@W2 and LN in MFMA C-layout. ----
__global__ __launch_bounds__(256) void k_node2(const int* __restrict__ cursor,
                                               const unsigned* __restrict__ recs,
                                               const unsigned* __restrict__ x1b,
                                               const float* __restrict__ disf,
                                               const int* __restrict__ spillCnt,
                                               const int* __restrict__ spill_d,
                                               const int* __restrict__ spill_r,
                                               const float* __restrict__ b2,
                                               const float* __restrict__ g2,
                                               const float* __restrict__ beta2,
                                               const unsigned short* __restrict__ Wb,
                                               float* __restrict__ out, int N) {
    // per-wave 16x128 bf16 tile, row stride 68 words (272 B): conflict-free b128 pattern
    __shared__ unsigned tileA[4][16 * 68];
    int wv = threadIdx.x >> 6;
    int lane = threadIdx.x & 63;
    int qtr = lane >> 4;
    int l = lane & 15;
    int qbase = lane & 48;
    int wbase = (blockIdx.x * 4 + wv) * 16;
    unsigned* myT = &tileA[wv][0];
    // ---- prefetch setup for all 4 row-groups (independent loads, all in flight) ----
    unsigned rvA[4], rvB[4];
    float diA[4];
    uint4 xvA[4];
    int dgA[4];
#pragma unroll
    for (int k = 0; k < 4; k++) {
        int i = wbase + k * 4 + qtr;
        int ii = (i < N) ? i : 0;
        dgA[k] = (i < N) ? cursor[ii] : 0;
        rvA[k] = recs[(size_t)ii * CAP + l];
        rvB[k] = recs[(size_t)ii * CAP + 16 + l];
        diA[k] = disf[ii];
        xvA[k] = *(const uint4*)(x1b + (size_t)ii * 64 + l * 4);
    }
#pragma unroll 1
    for (int k = 0; k < 4; k++) {
        int rr = k * 4 + qtr;          // local row 0..15
        int i = wbase + rr;
        uint4 pk = make_uint4(0, 0, 0, 0);
        if (i < N) {
            int dg = dgA[k];
            int dgc = (dg < CAP) ? dg : CAP;
            unsigned rv0 = rvA[k];
            unsigned rv1 = rvB[k];
            float a0 = 0.f, a1 = 0.f, a2 = 0.f, a3 = 0.f, a4 = 0.f, a5 = 0.f, a6 = 0.f, a7 = 0.f;
            for (int j0 = 0; j0 < dgc; j0 += 8) {
                unsigned rvs = (j0 < 16) ? rv0 : rv1;
                uint4 buf[8]; float fb[8]; float nn[8];
#pragma unroll
                for (int q = 0; q < 8; q++) {
                    int e = j0 + q;
                    int ec = (e < dgc) ? e : (dgc - 1);
                    unsigned rec = __shfl(rvs, qbase + (ec & 15), 64);
                    unsigned s = rec & 0xFFFFu;
                    nn[q] = (e < dgc) ? 1.f : 0.f;
                    buf[q] = *(const uint4*)(x1b + (size_t)s * 64 + l * 4);
                    fb[q] = disf[s];
                }
#pragma unroll
                for (int q = 0; q < 8; q++) {
                    float n = fb[q] * nn[q];
                    uint4 a = buf[q];
                    a0 += bflo(a.x) * n; a1 += bfhi(a.x) * n;
                    a2 += bflo(a.y) * n; a3 += bfhi(a.y) * n;
                    a4 += bflo(a.z) * n; a5 += bfhi(a.z) * n;
                    a6 += bflo(a.w) * n; a7 += bfhi(a.w) * n;
                }
            }
            if (dg > CAP) {   // rare spill path
                int sc = *spillCnt; if (sc > SPILL_MAX) sc = SPILL_MAX;
                for (int j = 0; j < sc; j++) {
                    if (spill_d[j] == i) {
                        unsigned s = (unsigned)spill_r[j] & 0xFFFFu;
                        float n = disf[s];
                        uint4 a = *(const uint4*)(x1b + (size_t)s * 64 + l * 4);
                        a0 += bflo(a.x) * n; a1 += bfhi(a.x) * n;
                        a2 += bflo(a.y) * n; a3 += bfhi(a.y) * n;
                        a4 += bflo(a.z) * n; a5 += bfhi(a.z) * n;
                        a6 += bflo(a.w) * n; a7 += bfhi(a.w) * n;
                    }
                }
            }
            float di = diA[k];
            uint4 xv = xvA[k];
            float z0 = a0 + di * bflo(xv.x);
            float z1 = a1 + di * bfhi(xv.x);
            float z2 = a2 + di * bflo(xv.y);
            float z3 = a3 + di * bfhi(xv.y);
            float z4 = a4 + di * bflo(xv.z);
            float z5 = a5 + di * bfhi(xv.z);
            float z6 = a6 + di * bflo(xv.w);
            float z7 = a7 + di * bfhi(xv.w);
            pk.x = (unsigned)f2bf(z0) | ((unsigned)f2bf(z1) << 16);
            pk.y = (unsigned)f2bf(z2) | ((unsigned)f2bf(z3) << 16);
            pk.z = (unsigned)f2bf(z4) | ((unsigned)f2bf(z5) << 16);
            pk.w = (unsigned)f2bf(z6) | ((unsigned)f2bf(z7) << 16);
        }
        *(uint4*)(myT + rr * 68 + l * 4) = pk;
    }
    __syncthreads();
    // ---- per-wave GEMM: 16 rows x 128 cols, 8 col-tiles x 4 k-slices ----
    short8 afr[4];
    const char* tb = (const char*)myT;
#pragma unroll
    for (int ks = 0; ks < 4; ks++)
        afr[ks] = *(const short8*)(tb + l * 272 + ks * 64 + qtr * 16);
    const short8* bp = (const short8*)Wb;
    float4v acc[8];
#pragma unroll
    for (int nt = 0; nt < 8; nt++) {
        float4v a = {0.f, 0.f, 0.f, 0.f};
#pragma unroll
        for (int ks = 0; ks < 4; ks++)
            a = __builtin_amdgcn_mfma_f32_16x16x32_bf16(afr[ks], bp[(nt * 4 + ks) * 64 + lane], a, 0, 0, 0);
        acc[nt] = a;
    }
    // ---- epilogue in MFMA C-layout: lane (qtr=quad, l=col) holds rows qtr*4+r, col nt*16+l ----
    float dvarr[4];
    {
        float4 dv4 = *(const float4*)(disf + wbase + qtr * 4);
        dvarr[0] = dv4.x; dvarr[1] = dv4.y; dvarr[2] = dv4.z; dvarr[3] = dv4.w;
    }
#pragma unroll
    for (int r = 0; r < 4; r++) {
        int rowg = wbase + qtr * 4 + r;
        if (rowg < N) {
            float di = dvarr[r];
            float vv[8]; float sum = 0.f;
#pragma unroll
            for (int nt = 0; nt < 8; nt++) {
                unsigned xw = x1b[(size_t)rowg * 64 + nt * 8 + (l >> 1)];
                float xr = (l & 1) ? bfhi(xw) : bflo(xw);
                vv[nt] = xr + di * acc[nt][r] + b2[nt * 16 + l];
                sum += vv[nt];
            }
#pragma unroll
            for (int o = 8; o >= 1; o >>= 1) sum += __shfl_xor(sum, o, 64);
            float mu = sum * (1.f / DD);
            float ss = 0.f;
#pragma unroll
            for (int nt = 0; nt < 8; nt++) { float d = vv[nt] - mu; vv[nt] = d; ss += d * d; }
#pragma unroll
            for (int o = 8; o >= 1; o >>= 1) ss += __shfl_xor(ss, o, 64);
            float rstd = rsqrtf(ss * (1.f / DD) + 1e-5f);
#pragma unroll
            for (int nt = 0; nt < 8; nt++)
                out[(size_t)rowg * DD + nt * 16 + l] = vv[nt] * rstd * g2[nt * 16 + l] + beta2[nt * 16 + l];
        }
    }
}

extern "C" void kernel_launch(void* const* d_in, const int* in_sizes, int n_in,
                              void* d_out, int out_size, void* d_ws, size_t ws_size,
                              hipStream_t stream) {
    const int* node_ids = (const int*)d_in[0];
    const int* edge_index = (const int*)d_in[1];
    const float* emb   = (const float*)d_in[2];
    const float* W1    = (const float*)d_in[3];
    const float* b1    = (const float*)d_in[4];
    const float* W2    = (const float*)d_in[5];
    const float* b2    = (const float*)d_in[6];
    const float* g1    = (const float*)d_in[7];
    const float* beta1 = (const float*)d_in[8];
    const float* g2    = (const float*)d_in[9];
    const float* beta2 = (const float*)d_in[10];
    const int N = in_sizes[0];
    const int E = in_sizes[1] / 2;
    const int* srcp = edge_index;
    const int* dstp = edge_index + E;
    float* out = (float*)d_out;

    char* base = (char*)d_ws;
    size_t off = 0;
    auto carve = [&](size_t bytes) -> void* {
        void* p = base + off;
        off += (bytes + 255) & ~(size_t)255;
        return p;
    };
    int*      meta   = (int*)carve((size_t)(N + 17) * 4);   // cursor[N+16] + spillCnt
    int*      cursor = meta;
    int*      spillCnt = meta + N + 16;
    int*      spill_d = (int*)carve((size_t)SPILL_MAX * 4);
    int*      spill_r = (int*)carve((size_t)SPILL_MAX * 4);
    unsigned* recs   = (unsigned*)carve((size_t)N * CAP * 4);
    unsigned* embW1b = (unsigned*)carve((size_t)512 * 64 * 4);
    unsigned* x1b    = (unsigned*)carve((size_t)(N + 64) * 64 * 4);
    float*    disf   = (float*)carve((size_t)(N + 64) * 4);
    unsigned short* Wb = (unsigned short*)carve((size_t)DD * DD * 2);
    (void)ws_size; (void)n_in; (void)out_size;

    const int TB = 256;
    const int Hb = (E + 511) / 512;           // bucket segment blocks: 2 edges/thread

    hipMemsetAsync(meta, 0, (size_t)(N + 17) * 4, stream);
    k_init<<<136 + Hb, TB, 0, stream>>>(emb, W1, W2, embW1b, Wb,
                                        srcp, dstp, node_ids, cursor, recs,
                                        spillCnt, spill_d, spill_r, E);

    long long tn = (long long)((N + 3) / 4) * 64;   // one wave per 4 nodes
    int nodeBlocks = (int)((tn + TB - 1) / TB);
    k_node1<<<nodeBlocks, TB, 0, stream>>>(cursor, recs, node_ids, emb, embW1b,
                                           spillCnt, spill_d, spill_r,
                                           b1, g1, beta1, x1b, disf, N);
    int blocks64 = (N + 63) / 64;             // 64 nodes per 256-thread block (16/wave)
    k_node2<<<blocks64, TB, 0, stream>>>(cursor, recs, x1b, disf,
                                         spillCnt, spill_d, spill_r,
                                         b2, g2, beta2, Wb, out, N);
}

// Round 6
// 174.651 us; speedup vs baseline: 1.0220x; 1.0220x over previous
//
#include <hip/hip_runtime.h>

#define DD 128
#define CAP 32
#define SPILL_MAX 4096

typedef __attribute__((ext_vector_type(8))) short short8;
typedef __attribute__((ext_vector_type(4))) float float4v;

static __device__ __forceinline__ unsigned short f2bf(float x) {
    unsigned u = __builtin_bit_cast(unsigned, x);
    u += 0x7fffu + ((u >> 16) & 1u);   // RNE
    return (unsigned short)(u >> 16);
}
static __device__ __forceinline__ float bflo(unsigned u) {
    return __builtin_bit_cast(float, u << 16);
}
static __device__ __forceinline__ float bfhi(unsigned u) {
    return __builtin_bit_cast(float, u & 0xffff0000u);
}

// ---- fused init: [0,128) emb@W1 bf16 table; [128,136) W2 swizzle; [136,136+Hb) edge bucketing ----
__global__ __launch_bounds__(256) void k_init(const float* __restrict__ emb,
                                              const float* __restrict__ W1,
                                              const float* __restrict__ W2,
                                              unsigned* __restrict__ embW1b,
                                              unsigned short* __restrict__ Wb,
                                              const int* __restrict__ src,
                                              const int* __restrict__ dst,
                                              const int* __restrict__ node_ids,
                                              int* __restrict__ cursor,
                                              unsigned* __restrict__ recs,
                                              int* __restrict__ spillCnt,
                                              int* __restrict__ spill_d,
                                              int* __restrict__ spill_r, int E) {
    int blk = blockIdx.x;
    if (blk < 128) {
        int w = threadIdx.x >> 6;
        int t = threadIdx.x & 63;
        int p = blk * 4 + w;
        int c0 = t * 2, c1 = t * 2 + 1;
        float s0 = 0.f, s1 = 0.f;
#pragma unroll 8
        for (int k = 0; k < DD; k++) {
            float e = emb[p * DD + k];
            s0 += e * W1[k * DD + c0];
            s1 += e * W1[k * DD + c1];
        }
        embW1b[p * 64 + t] = (unsigned)f2bf(s0) | ((unsigned)f2bf(s1) << 16);
    } else if (blk < 136) {
        int t = (blk - 128) * 256 + threadIdx.x;   // 0..2047: (nt, ks, lane)
        int nt = t >> 8, ks = (t >> 6) & 3, lane = t & 63;
        int n = nt * 16 + (lane & 15);
        int kbase = ks * 32 + (lane >> 4) * 8;
        unsigned short* o = Wb + (size_t)t * 8;
#pragma unroll
        for (int j = 0; j < 8; j++)
            o[j] = f2bf(W2[(kbase + j) * DD + n]);
    } else {
        int base = ((blk - 136) * 256 + threadIdx.x) * 4;
        if (base >= E) return;
#pragma unroll
        for (int u = 0; u < 4; u++) {
            int e = base + u;
            if (e >= E) break;
            int s = src[e], d = dst[e];
            unsigned rec = (unsigned)s | ((unsigned)node_ids[s] << 16);
            int pos = atomicAdd(&cursor[d], 1);
            if (pos < CAP) {
                recs[(size_t)d * CAP + pos] = rec;
            } else {
                int sp = atomicAdd(spillCnt, 1);
                if (sp < SPILL_MAX) { spill_d[sp] = d; spill_r[sp] = (int)rec; }
            }
        }
    }
}

// ---- layer 1: aggregation (depth-8 pipelined loads) + LN -> x1b (bf16) + disf ----
__global__ __launch_bounds__(256) void k_node1(const int* __restrict__ cursor,
                                               const unsigned* __restrict__ recs,
                                               const int* __restrict__ node_ids,
                                               const float* __restrict__ emb,
                                               const unsigned* __restrict__ embW1b,
                                               const int* __restrict__ spillCnt,
                                               const int* __restrict__ spill_d,
                                               const int* __restrict__ spill_r,
                                               const float* __restrict__ b1,
                                               const float* __restrict__ g1,
                                               const float* __restrict__ beta1,
                                               unsigned* __restrict__ x1b,
                                               float* __restrict__ disf, int N) {
    int gid = blockIdx.x * blockDim.x + threadIdx.x;
    int wave = gid >> 6;
    int lane = threadIdx.x & 63;
    int qtr = lane >> 4;
    int l = lane & 15;
    int qbase = lane & 48;
    int i = wave * 4 + qtr;
    if (i >= N) return;
    int dg = cursor[i];
    int dgc = (dg < CAP) ? dg : CAP;
    unsigned rv0 = recs[(size_t)i * CAP + l];
    unsigned rv1 = recs[(size_t)i * CAP + 16 + l];
    int c = l * 8;
    float a0 = 0.f, a1 = 0.f, a2 = 0.f, a3 = 0.f, a4 = 0.f, a5 = 0.f, a6 = 0.f, a7 = 0.f;
    for (int j0 = 0; j0 < dgc; j0 += 8) {
        unsigned rvs = (j0 < 16) ? rv0 : rv1;
        uint4 buf[8]; int cb[8]; float nn[8];
#pragma unroll
        for (int q = 0; q < 8; q++) {
            int e = j0 + q;
            int ec = (e < dgc) ? e : (dgc - 1);
            unsigned rec = __shfl(rvs, qbase + (ec & 15), 64);
            nn[q] = (e < dgc) ? 1.f : 0.f;
            buf[q] = *(const uint4*)(embW1b + ((rec >> 16) & 511u) * 64 + l * 4);
            cb[q] = cursor[rec & 0xFFFFu];
        }
#pragma unroll
        for (int q = 0; q < 8; q++) {
            float n = rsqrtf((float)cb[q] + 1.f) * nn[q];
            uint4 a = buf[q];
            a0 += bflo(a.x) * n; a1 += bfhi(a.x) * n;
            a2 += bflo(a.y) * n; a3 += bfhi(a.y) * n;
            a4 += bflo(a.z) * n; a5 += bfhi(a.z) * n;
            a6 += bflo(a.w) * n; a7 += bfhi(a.w) * n;
        }
    }
    if (dg > CAP) {   // rare spill path
        int sc = *spillCnt; if (sc > SPILL_MAX) sc = SPILL_MAX;
        for (int j = 0; j < sc; j++) {
            if (spill_d[j] == i) {
                unsigned rec = (unsigned)spill_r[j];
                int s = rec & 0xFFFFu;
                float n = rsqrtf((float)cursor[s] + 1.0f);
                uint4 a = *(const uint4*)(embW1b + ((rec >> 16) & 511u) * 64 + l * 4);
                a0 += bflo(a.x) * n; a1 += bfhi(a.x) * n;
                a2 += bflo(a.y) * n; a3 += bfhi(a.y) * n;
                a4 += bflo(a.z) * n; a5 += bfhi(a.z) * n;
                a6 += bflo(a.w) * n; a7 += bfhi(a.w) * n;
            }
        }
    }
    float di = rsqrtf((float)dg + 1.0f);
    int pid = node_ids[i];
    float4 ev0 = *(const float4*)(emb + (size_t)pid * DD + c);
    float4 ev1 = *(const float4*)(emb + (size_t)pid * DD + c + 4);
    uint4 hw = *(const uint4*)(embW1b + pid * 64 + l * 4);
    float4 bb0 = *(const float4*)(b1 + c);
    float4 bb1 = *(const float4*)(b1 + c + 4);
    float v0 = ev0.x + di * (a0 + di * bflo(hw.x)) + bb0.x;
    float v1 = ev0.y + di * (a1 + di * bfhi(hw.x)) + bb0.y;
    float v2 = ev0.z + di * (a2 + di * bflo(hw.y)) + bb0.z;
    float v3 = ev0.w + di * (a3 + di * bfhi(hw.y)) + bb0.w;
    float v4 = ev1.x + di * (a4 + di * bflo(hw.z)) + bb1.x;
    float v5 = ev1.y + di * (a5 + di * bfhi(hw.z)) + bb1.y;
    float v6 = ev1.z + di * (a6 + di * bflo(hw.w)) + bb1.z;
    float v7 = ev1.w + di * (a7 + di * bfhi(hw.w)) + bb1.w;
    float sum = v0 + v1 + v2 + v3 + v4 + v5 + v6 + v7;
#pragma unroll
    for (int o = 8; o >= 1; o >>= 1) sum += __shfl_xor(sum, o, 64);
    float mu = sum * (1.f / DD);
    float d0 = v0 - mu, d1 = v1 - mu, d2 = v2 - mu, d3 = v3 - mu;
    float d4 = v4 - mu, d5 = v5 - mu, d6 = v6 - mu, d7 = v7 - mu;
    float ss = d0 * d0 + d1 * d1 + d2 * d2 + d3 * d3 + d4 * d4 + d5 * d5 + d6 * d6 + d7 * d7;
#pragma unroll
    for (int o = 8; o >= 1; o >>= 1) ss += __shfl_xor(ss, o, 64);
    float r = rsqrtf(ss * (1.f / DD) + 1e-5f);
    float4 gg0 = *(const float4*)(g1 + c);
    float4 gg1 = *(const float4*)(g1 + c + 4);
    float4 be0 = *(const float4*)(beta1 + c);
    float4 be1 = *(const float4*)(beta1 + c + 4);
    float o0 = d0 * r * gg0.x + be0.x;
    float o1 = d1 * r * gg0.y + be0.y;
    float o2 = d2 * r * gg0.z + be0.z;
    float o3 = d3 * r * gg0.w + be0.w;
    float o4 = d4 * r * gg1.x + be1.x;
    float o5 = d5 * r * gg1.y + be1.y;
    float o6 = d6 * r * gg1.z + be1.z;
    float o7 = d7 * r * gg1.w + be1.w;
    uint4 pk;
    pk.x = (unsigned)f2bf(o0) | ((unsigned)f2bf(o1) << 16);
    pk.y = (unsigned)f2bf(o2) | ((unsigned)f2bf(o3) << 16);
    pk.z = (unsigned)f2bf(o4) | ((unsigned)f2bf(o5) << 16);
    pk.w = (unsigned)f2bf(o6) | ((unsigned)f2bf(o7) << 16);
    *(uint4*)(x1b + (size_t)i * 64 + l * 4) = pk;
    if (l == 0) disf[i] = di;
}

// ---- layer 2: each WAVE owns 8 nodes (halved serial length, 2x grid parallelism
//      vs 16/wave). 16-row MFMA tile keeps rows 8..15 zeroed (zero A-rows => zero
//      C-rows; MFMA util ~1%, waste is free). Epilogue: quads 0,1 only. ----
__global__ __launch_bounds__(256) void k_node2(const int* __restrict__ cursor,
                                               const unsigned* __restrict__ recs,
                                               const unsigned* __restrict__ x1b,
                                               const float* __restrict__ disf,
                                               const int* __restrict__ spillCnt,
                                               const int* __restrict__ spill_d,
                                               const int* __restrict__ spill_r,
                                               const float* __restrict__ b2,
                                               const float* __restrict__ g2,
                                               const float* __restrict__ beta2,
                                               const unsigned short* __restrict__ Wb,
                                               float* __restrict__ out, int N) {
    // per-wave 16x128 bf16 tile, row stride 68 words (272 B): conflict-free b128 pattern
    __shared__ unsigned tileA[4][16 * 68];
    int wv = threadIdx.x >> 6;
    int lane = threadIdx.x & 63;
    int qtr = lane >> 4;
    int l = lane & 15;
    int qbase = lane & 48;
    int wbase = (blockIdx.x * 4 + wv) * 8;     // 8 nodes per wave
    unsigned* myT = &tileA[wv][0];
#pragma unroll 1
    for (int k = 0; k < 4; k++) {
        int rr = k * 4 + qtr;                  // local row 0..15
        int i = (rr < 8) ? (wbase + rr) : N;   // rows 8..15 forced to zero path
        uint4 pk = make_uint4(0, 0, 0, 0);
        if (i < N) {
            int dg = cursor[i];
            int dgc = (dg < CAP) ? dg : CAP;
            unsigned rv0 = recs[(size_t)i * CAP + l];
            unsigned rv1 = recs[(size_t)i * CAP + 16 + l];
            float a0 = 0.f, a1 = 0.f, a2 = 0.f, a3 = 0.f, a4 = 0.f, a5 = 0.f, a6 = 0.f, a7 = 0.f;
            for (int j0 = 0; j0 < dgc; j0 += 8) {
                unsigned rvs = (j0 < 16) ? rv0 : rv1;
                uint4 buf[8]; float fb[8]; float nn[8];
#pragma unroll
                for (int q = 0; q < 8; q++) {
                    int e = j0 + q;
                    int ec = (e < dgc) ? e : (dgc - 1);
                    unsigned rec = __shfl(rvs, qbase + (ec & 15), 64);
                    unsigned s = rec & 0xFFFFu;
                    nn[q] = (e < dgc) ? 1.f : 0.f;
                    buf[q] = *(const uint4*)(x1b + (size_t)s * 64 + l * 4);
                    fb[q] = disf[s];
                }
#pragma unroll
                for (int q = 0; q < 8; q++) {
                    float n = fb[q] * nn[q];
                    uint4 a = buf[q];
                    a0 += bflo(a.x) * n; a1 += bfhi(a.x) * n;
                    a2 += bflo(a.y) * n; a3 += bfhi(a.y) * n;
                    a4 += bflo(a.z) * n; a5 += bfhi(a.z) * n;
                    a6 += bflo(a.w) * n; a7 += bfhi(a.w) * n;
                }
            }
            if (dg > CAP) {   // rare spill path
                int sc = *spillCnt; if (sc > SPILL_MAX) sc = SPILL_MAX;
                for (int j = 0; j < sc; j++) {
                    if (spill_d[j] == i) {
                        unsigned s = (unsigned)spill_r[j] & 0xFFFFu;
                        float n = disf[s];
                        uint4 a = *(const uint4*)(x1b + (size_t)s * 64 + l * 4);
                        a0 += bflo(a.x) * n; a1 += bfhi(a.x) * n;
                        a2 += bflo(a.y) * n; a3 += bfhi(a.y) * n;
                        a4 += bflo(a.z) * n; a5 += bfhi(a.z) * n;
                        a6 += bflo(a.w) * n; a7 += bfhi(a.w) * n;
                    }
                }
            }
            float di = disf[i];
            uint4 xv = *(const uint4*)(x1b + (size_t)i * 64 + l * 4);
            float z0 = a0 + di * bflo(xv.x);
            float z1 = a1 + di * bfhi(xv.x);
            float z2 = a2 + di * bflo(xv.y);
            float z3 = a3 + di * bfhi(xv.y);
            float z4 = a4 + di * bflo(xv.z);
            float z5 = a5 + di * bfhi(xv.z);
            float z6 = a6 + di * bflo(xv.w);
            float z7 = a7 + di * bfhi(xv.w);
            pk.x = (unsigned)f2bf(z0) | ((unsigned)f2bf(z1) << 16);
            pk.y = (unsigned)f2bf(z2) | ((unsigned)f2bf(z3) << 16);
            pk.z = (unsigned)f2bf(z4) | ((unsigned)f2bf(z5) << 16);
            pk.w = (unsigned)f2bf(z6) | ((unsigned)f2bf(z7) << 16);
        }
        *(uint4*)(myT + rr * 68 + l * 4) = pk;
    }
    __syncthreads();
    // ---- per-wave GEMM: 16 rows x 128 cols (rows 8..15 zero), 8 col-tiles x 4 k-slices ----
    short8 afr[4];
    const char* tb = (const char*)myT;
#pragma unroll
    for (int ks = 0; ks < 4; ks++)
        afr[ks] = *(const short8*)(tb + l * 272 + ks * 64 + qtr * 16);
    const short8* bp = (const short8*)Wb;
    float4v acc[8];
#pragma unroll
    for (int nt = 0; nt < 8; nt++) {
        float4v a = {0.f, 0.f, 0.f, 0.f};
#pragma unroll
        for (int ks = 0; ks < 4; ks++)
            a = __builtin_amdgcn_mfma_f32_16x16x32_bf16(afr[ks], bp[(nt * 4 + ks) * 64 + lane], a, 0, 0, 0);
        acc[nt] = a;
    }
    // ---- epilogue in MFMA C-layout: lane (qtr=quad, l=col) holds rows qtr*4+r, col nt*16+l.
    //      Only local rows 0..7 (qtr 0,1) are real. ----
    float dvarr[4];
    {
        float4 dv4 = *(const float4*)(disf + wbase + qtr * 4);
        dvarr[0] = dv4.x; dvarr[1] = dv4.y; dvarr[2] = dv4.z; dvarr[3] = dv4.w;
    }
#pragma unroll
    for (int r = 0; r < 4; r++) {
        int rowg = wbase + qtr * 4 + r;
        if (qtr < 2 && rowg < N) {
            float di = dvarr[r];
            float vv[8]; float sum = 0.f;
#pragma unroll
            for (int nt = 0; nt < 8; nt++) {
                unsigned xw = x1b[(size_t)rowg * 64 + nt * 8 + (l >> 1)];
                float xr = (l & 1) ? bfhi(xw) : bflo(xw);
                vv[nt] = xr + di * acc[nt][r] + b2[nt * 16 + l];
                sum += vv[nt];
            }
#pragma unroll
            for (int o = 8; o >= 1; o >>= 1) sum += __shfl_xor(sum, o, 64);
            float mu = sum * (1.f / DD);
            float ss = 0.f;
#pragma unroll
            for (int nt = 0; nt < 8; nt++) { float d = vv[nt] - mu; vv[nt] = d; ss += d * d; }
#pragma unroll
            for (int o = 8; o >= 1; o >>= 1) ss += __shfl_xor(ss, o, 64);
            float rstd = rsqrtf(ss * (1.f / DD) + 1e-5f);
#pragma unroll
            for (int nt = 0; nt < 8; nt++)
                out[(size_t)rowg * DD + nt * 16 + l] = vv[nt] * rstd * g2[nt * 16 + l] + beta2[nt * 16 + l];
        }
    }
}

extern "C" void kernel_launch(void* const* d_in, const int* in_sizes, int n_in,
                              void* d_out, int out_size, void* d_ws, size_t ws_size,
                              hipStream_t stream) {
    const int* node_ids = (const int*)d_in[0];
    const int* edge_index = (const int*)d_in[1];
    const float* emb   = (const float*)d_in[2];
    const float* W1    = (const float*)d_in[3];
    const float* b1    = (const float*)d_in[4];
    const float* W2    = (const float*)d_in[5];
    const float* b2    = (const float*)d_in[6];
    const float* g1    = (const float*)d_in[7];
    const float* beta1 = (const float*)d_in[8];
    const float* g2    = (const float*)d_in[9];
    const float* beta2 = (const float*)d_in[10];
    const int N = in_sizes[0];
    const int E = in_sizes[1] / 2;
    const int* srcp = edge_index;
    const int* dstp = edge_index + E;
    float* out = (float*)d_out;

    char* base = (char*)d_ws;
    size_t off = 0;
    auto carve = [&](size_t bytes) -> void* {
        void* p = base + off;
        off += (bytes + 255) & ~(size_t)255;
        return p;
    };
    int*      meta   = (int*)carve((size_t)(N + 17) * 4);   // cursor[N+16] + spillCnt
    int*      cursor = meta;
    int*      spillCnt = meta + N + 16;
    int*      spill_d = (int*)carve((size_t)SPILL_MAX * 4);
    int*      spill_r = (int*)carve((size_t)SPILL_MAX * 4);
    unsigned* recs   = (unsigned*)carve((size_t)N * CAP * 4);
    unsigned* embW1b = (unsigned*)carve((size_t)512 * 64 * 4);
    unsigned* x1b    = (unsigned*)carve((size_t)(N + 64) * 64 * 4);
    float*    disf   = (float*)carve((size_t)(N + 64) * 4);
    unsigned short* Wb = (unsigned short*)carve((size_t)DD * DD * 2);
    (void)ws_size; (void)n_in; (void)out_size;

    const int TB = 256;
    const int Hb = (E + 1023) / 1024;         // bucket segment blocks: 4 edges/thread

    hipMemsetAsync(meta, 0, (size_t)(N + 17) * 4, stream);
    k_init<<<136 + Hb, TB, 0, stream>>>(emb, W1, W2, embW1b, Wb,
                                        srcp, dstp, node_ids, cursor, recs,
                                        spillCnt, spill_d, spill_r, E);

    long long tn = (long long)((N + 3) / 4) * 64;   // one wave per 4 nodes
    int nodeBlocks = (int)((tn + TB - 1) / TB);
    k_node1<<<nodeBlocks, TB, 0, stream>>>(cursor, recs, node_ids, emb, embW1b,
                                           spillCnt, spill_d, spill_r,
                                           b1, g1, beta1, x1b, disf, N);
    int blocks32 = (N + 31) / 32;             // 32 nodes per 256-thread block (8/wave)
    k_node2<<<blocks32, TB, 0, stream>>>(cursor, recs, x1b, disf,
                                         spillCnt, spill_d, spill_r,
                                         b2, g2, beta2, Wb, out, N);
}

// Round 7
// 167.253 us; speedup vs baseline: 1.0672x; 1.0442x over previous
//
#include <hip/hip_runtime.h>

#define DD 128
#define CAP 32
#define SPILL_MAX 4096

typedef __attribute__((ext_vector_type(8))) short short8;
typedef __attribute__((ext_vector_type(4))) float float4v;

static __device__ __forceinline__ unsigned short f2bf(float x) {
    unsigned u = __builtin_bit_cast(unsigned, x);
    u += 0x7fffu + ((u >> 16) & 1u);   // RNE
    return (unsigned short)(u >> 16);
}
static __device__ __forceinline__ float bflo(unsigned u) {
    return __builtin_bit_cast(float, u << 16);
}
static __device__ __forceinline__ float bfhi(unsigned u) {
    return __builtin_bit_cast(float, u & 0xffff0000u);
}

// ---- fused init: [0,128) emb@W1 bf16 table; [128,136) W2 swizzle; [136,136+Hb) edge bucketing ----
__global__ __launch_bounds__(256) void k_init(const float* __restrict__ emb,
                                              const float* __restrict__ W1,
                                              const float* __restrict__ W2,
                                              unsigned* __restrict__ embW1b,
                                              unsigned short* __restrict__ Wb,
                                              const int* __restrict__ src,
                                              const int* __restrict__ dst,
                                              const int* __restrict__ node_ids,
                                              int* __restrict__ cursor,
                                              unsigned* __restrict__ recs,
                                              int* __restrict__ spillCnt,
                                              int* __restrict__ spill_d,
                                              int* __restrict__ spill_r, int E) {
    int blk = blockIdx.x;
    if (blk < 128) {
        int w = threadIdx.x >> 6;
        int t = threadIdx.x & 63;
        int p = blk * 4 + w;
        int c0 = t * 2, c1 = t * 2 + 1;
        float s0 = 0.f, s1 = 0.f;
#pragma unroll 8
        for (int k = 0; k < DD; k++) {
            float e = emb[p * DD + k];
            s0 += e * W1[k * DD + c0];
            s1 += e * W1[k * DD + c1];
        }
        embW1b[p * 64 + t] = (unsigned)f2bf(s0) | ((unsigned)f2bf(s1) << 16);
    } else if (blk < 136) {
        int t = (blk - 128) * 256 + threadIdx.x;   // 0..2047: (nt, ks, lane)
        int nt = t >> 8, ks = (t >> 6) & 3, lane = t & 63;
        int n = nt * 16 + (lane & 15);
        int kbase = ks * 32 + (lane >> 4) * 8;
        unsigned short* o = Wb + (size_t)t * 8;
#pragma unroll
        for (int j = 0; j < 8; j++)
            o[j] = f2bf(W2[(kbase + j) * DD + n]);
    } else {
        int base = ((blk - 136) * 256 + threadIdx.x) * 4;
        if (base >= E) return;
#pragma unroll
        for (int u = 0; u < 4; u++) {
            int e = base + u;
            if (e >= E) break;
            int s = src[e], d = dst[e];
            unsigned rec = (unsigned)s | ((unsigned)node_ids[s] << 16);
            int pos = atomicAdd(&cursor[d], 1);
            if (pos < CAP) {
                recs[(size_t)d * CAP + pos] = rec;
            } else {
                int sp = atomicAdd(spillCnt, 1);
                if (sp < SPILL_MAX) { spill_d[sp] = d; spill_r[sp] = (int)rec; }
            }
        }
    }
}

// ---- layer 1: aggregation (depth-8 pipelined loads) + LN -> x1b (bf16) + disf ----
// __launch_bounds__(256,4): grid gives >=4 blocks/CU here; allow 128 VGPR so the
// 8-deep load batch actually stays in flight (at 56 VGPR the compiler serializes it).
__global__ __launch_bounds__(256, 4) void k_node1(const int* __restrict__ cursor,
                                               const unsigned* __restrict__ recs,
                                               const int* __restrict__ node_ids,
                                               const float* __restrict__ emb,
                                               const unsigned* __restrict__ embW1b,
                                               const int* __restrict__ spillCnt,
                                               const int* __restrict__ spill_d,
                                               const int* __restrict__ spill_r,
                                               const float* __restrict__ b1,
                                               const float* __restrict__ g1,
                                               const float* __restrict__ beta1,
                                               unsigned* __restrict__ x1b,
                                               float* __restrict__ disf, int N) {
    int gid = blockIdx.x * blockDim.x + threadIdx.x;
    int wave = gid >> 6;
    int lane = threadIdx.x & 63;
    int qtr = lane >> 4;
    int l = lane & 15;
    int qbase = lane & 48;
    int i = wave * 4 + qtr;
    if (i >= N) return;
    int dg = cursor[i];
    int dgc = (dg < CAP) ? dg : CAP;
    unsigned rv0 = recs[(size_t)i * CAP + l];
    unsigned rv1 = recs[(size_t)i * CAP + 16 + l];
    int c = l * 8;
    float a0 = 0.f, a1 = 0.f, a2 = 0.f, a3 = 0.f, a4 = 0.f, a5 = 0.f, a6 = 0.f, a7 = 0.f;
    for (int j0 = 0; j0 < dgc; j0 += 8) {
        unsigned rvs = (j0 < 16) ? rv0 : rv1;
        const uint4* ap[8]; const int* cp[8]; float nn[8];
#pragma unroll
        for (int q = 0; q < 8; q++) {
            int e = j0 + q;
            int ec = (e < dgc) ? e : (dgc - 1);
            unsigned rec = __shfl(rvs, qbase + (ec & 15), 64);
            nn[q] = (e < dgc) ? 1.f : 0.f;
            ap[q] = (const uint4*)(embW1b + ((rec >> 16) & 511u) * 64 + l * 4);
            cp[q] = cursor + (rec & 0xFFFFu);
        }
        uint4 buf[8]; int cb[8];
#pragma unroll
        for (int q = 0; q < 8; q++) { buf[q] = *ap[q]; cb[q] = *cp[q]; }
#pragma unroll
        for (int q = 0; q < 8; q++) {
            float n = rsqrtf((float)cb[q] + 1.f) * nn[q];
            uint4 a = buf[q];
            a0 += bflo(a.x) * n; a1 += bfhi(a.x) * n;
            a2 += bflo(a.y) * n; a3 += bfhi(a.y) * n;
            a4 += bflo(a.z) * n; a5 += bfhi(a.z) * n;
            a6 += bflo(a.w) * n; a7 += bfhi(a.w) * n;
        }
    }
    if (dg > CAP) {   // rare spill path
        int sc = *spillCnt; if (sc > SPILL_MAX) sc = SPILL_MAX;
        for (int j = 0; j < sc; j++) {
            if (spill_d[j] == i) {
                unsigned rec = (unsigned)spill_r[j];
                int s = rec & 0xFFFFu;
                float n = rsqrtf((float)cursor[s] + 1.0f);
                uint4 a = *(const uint4*)(embW1b + ((rec >> 16) & 511u) * 64 + l * 4);
                a0 += bflo(a.x) * n; a1 += bfhi(a.x) * n;
                a2 += bflo(a.y) * n; a3 += bfhi(a.y) * n;
                a4 += bflo(a.z) * n; a5 += bfhi(a.z) * n;
                a6 += bflo(a.w) * n; a7 += bfhi(a.w) * n;
            }
        }
    }
    float di = rsqrtf((float)dg + 1.0f);
    int pid = node_ids[i];
    float4 ev0 = *(const float4*)(emb + (size_t)pid * DD + c);
    float4 ev1 = *(const float4*)(emb + (size_t)pid * DD + c + 4);
    uint4 hw = *(const uint4*)(embW1b + pid * 64 + l * 4);
    float4 bb0 = *(const float4*)(b1 + c);
    float4 bb1 = *(const float4*)(b1 + c + 4);
    float v0 = ev0.x + di * (a0 + di * bflo(hw.x)) + bb0.x;
    float v1 = ev0.y + di * (a1 + di * bfhi(hw.x)) + bb0.y;
    float v2 = ev0.z + di * (a2 + di * bflo(hw.y)) + bb0.z;
    float v3 = ev0.w + di * (a3 + di * bfhi(hw.y)) + bb0.w;
    float v4 = ev1.x + di * (a4 + di * bflo(hw.z)) + bb1.x;
    float v5 = ev1.y + di * (a5 + di * bfhi(hw.z)) + bb1.y;
    float v6 = ev1.z + di * (a6 + di * bflo(hw.w)) + bb1.z;
    float v7 = ev1.w + di * (a7 + di * bfhi(hw.w)) + bb1.w;
    float sum = v0 + v1 + v2 + v3 + v4 + v5 + v6 + v7;
#pragma unroll
    for (int o = 8; o >= 1; o >>= 1) sum += __shfl_xor(sum, o, 64);
    float mu = sum * (1.f / DD);
    float d0 = v0 - mu, d1 = v1 - mu, d2 = v2 - mu, d3 = v3 - mu;
    float d4 = v4 - mu, d5 = v5 - mu, d6 = v6 - mu, d7 = v7 - mu;
    float ss = d0 * d0 + d1 * d1 + d2 * d2 + d3 * d3 + d4 * d4 + d5 * d5 + d6 * d6 + d7 * d7;
#pragma unroll
    for (int o = 8; o >= 1; o >>= 1) ss += __shfl_xor(ss, o, 64);
    float r = rsqrtf(ss * (1.f / DD) + 1e-5f);
    float4 gg0 = *(const float4*)(g1 + c);
    float4 gg1 = *(const float4*)(g1 + c + 4);
    float4 be0 = *(const float4*)(beta1 + c);
    float4 be1 = *(const float4*)(beta1 + c + 4);
    float o0 = d0 * r * gg0.x + be0.x;
    float o1 = d1 * r * gg0.y + be0.y;
    float o2 = d2 * r * gg0.z + be0.z;
    float o3 = d3 * r * gg0.w + be0.w;
    float o4 = d4 * r * gg1.x + be1.x;
    float o5 = d5 * r * gg1.y + be1.y;
    float o6 = d6 * r * gg1.z + be1.z;
    float o7 = d7 * r * gg1.w + be1.w;
    uint4 pk;
    pk.x = (unsigned)f2bf(o0) | ((unsigned)f2bf(o1) << 16);
    pk.y = (unsigned)f2bf(o2) | ((unsigned)f2bf(o3) << 16);
    pk.z = (unsigned)f2bf(o4) | ((unsigned)f2bf(o5) << 16);
    pk.w = (unsigned)f2bf(o6) | ((unsigned)f2bf(o7) << 16);
    *(uint4*)(x1b + (size_t)i * 64 + l * 4) = pk;
    if (l == 0) disf[i] = di;
}

// ---- layer 2: each WAVE owns 16 nodes; gather z rows (depth-8 pipelined,
//      disf-weighted) -> wave-private LDS tile -> per-wave MFMA z@W2 ->
//      LN in MFMA C-layout -> out. __launch_bounds__(256,4) as node1. ----
__global__ __launch_bounds__(256, 4) void k_node2(const int* __restrict__ cursor,
                                               const unsigned* __restrict__ recs,
                                               const unsigned* __restrict__ x1b,
                                               const float* __restrict__ disf,
                                               const int* __restrict__ spillCnt,
                                               const int* __restrict__ spill_d,
                                               const int* __restrict__ spill_r,
                                               const float* __restrict__ b2,
                                               const float* __restrict__ g2,
                                               const float* __restrict__ beta2,
                                               const unsigned short* __restrict__ Wb,
                                               float* __restrict__ out, int N) {
    // per-wave 16x128 bf16 tile, row stride 68 words (272 B): conflict-free b128 pattern
    __shared__ unsigned tileA[4][16 * 68];
    int wv = threadIdx.x >> 6;
    int lane = threadIdx.x & 63;
    int qtr = lane >> 4;
    int l = lane & 15;
    int qbase = lane & 48;
    int wbase = (blockIdx.x * 4 + wv) * 16;
    unsigned* myT = &tileA[wv][0];
#pragma unroll 1
    for (int k = 0; k < 4; k++) {
        int rr = k * 4 + qtr;          // local row 0..15
        int i = wbase + rr;
        uint4 pk = make_uint4(0, 0, 0, 0);
        if (i < N) {
            int dg = cursor[i];
            int dgc = (dg < CAP) ? dg : CAP;
            unsigned rv0 = recs[(size_t)i * CAP + l];
            unsigned rv1 = recs[(size_t)i * CAP + 16 + l];
            float a0 = 0.f, a1 = 0.f, a2 = 0.f, a3 = 0.f, a4 = 0.f, a5 = 0.f, a6 = 0.f, a7 = 0.f;
            for (int j0 = 0; j0 < dgc; j0 += 8) {
                unsigned rvs = (j0 < 16) ? rv0 : rv1;
                const uint4* ap[8]; const float* fp[8]; float nn[8];
#pragma unroll
                for (int q = 0; q < 8; q++) {
                    int e = j0 + q;
                    int ec = (e < dgc) ? e : (dgc - 1);
                    unsigned rec = __shfl(rvs, qbase + (ec & 15), 64);
                    unsigned s = rec & 0xFFFFu;
                    nn[q] = (e < dgc) ? 1.f : 0.f;
                    ap[q] = (const uint4*)(x1b + (size_t)s * 64 + l * 4);
                    fp[q] = disf + s;
                }
                uint4 buf[8]; float fb[8];
#pragma unroll
                for (int q = 0; q < 8; q++) { buf[q] = *ap[q]; fb[q] = *fp[q]; }
#pragma unroll
                for (int q = 0; q < 8; q++) {
                    float n = fb[q] * nn[q];
                    uint4 a = buf[q];
                    a0 += bflo(a.x) * n; a1 += bfhi(a.x) * n;
                    a2 += bflo(a.y) * n; a3 += bfhi(a.y) * n;
                    a4 += bflo(a.z) * n; a5 += bfhi(a.z) * n;
                    a6 += bflo(a.w) * n; a7 += bfhi(a.w) * n;
                }
            }
            if (dg > CAP) {   // rare spill path
                int sc = *spillCnt; if (sc > SPILL_MAX) sc = SPILL_MAX;
                for (int j = 0; j < sc; j++) {
                    if (spill_d[j] == i) {
                        unsigned s = (unsigned)spill_r[j] & 0xFFFFu;
                        float n = disf[s];
                        uint4 a = *(const uint4*)(x1b + (size_t)s * 64 + l * 4);
                        a0 += bflo(a.x) * n; a1 += bfhi(a.x) * n;
                        a2 += bflo(a.y) * n; a3 += bfhi(a.y) * n;
                        a4 += bflo(a.z) * n; a5 += bfhi(a.z) * n;
                        a6 += bflo(a.w) * n; a7 += bfhi(a.w) * n;
                    }
                }
            }
            float di = disf[i];
            uint4 xv = *(const uint4*)(x1b + (size_t)i * 64 + l * 4);
            float z0 = a0 + di * bflo(xv.x);
            float z1 = a1 + di * bfhi(xv.x);
            float z2 = a2 + di * bflo(xv.y);
            float z3 = a3 + di * bfhi(xv.y);
            float z4 = a4 + di * bflo(xv.z);
            float z5 = a5 + di * bfhi(xv.z);
            float z6 = a6 + di * bflo(xv.w);
            float z7 = a7 + di * bfhi(xv.w);
            pk.x = (unsigned)f2bf(z0) | ((unsigned)f2bf(z1) << 16);
            pk.y = (unsigned)f2bf(z2) | ((unsigned)f2bf(z3) << 16);
            pk.z = (unsigned)f2bf(z4) | ((unsigned)f2bf(z5) << 16);
            pk.w = (unsigned)f2bf(z6) | ((unsigned)f2bf(z7) << 16);
        }
        *(uint4*)(myT + rr * 68 + l * 4) = pk;
    }
    __syncthreads();
    // ---- per-wave GEMM: 16 rows x 128 cols, 8 col-tiles x 4 k-slices ----
    short8 afr[4];
    const char* tb = (const char*)myT;
#pragma unroll
    for (int ks = 0; ks < 4; ks++)
        afr[ks] = *(const short8*)(tb + l * 272 + ks * 64 + qtr * 16);
    const short8* bp = (const short8*)Wb;
    float4v acc[8];
#pragma unroll
    for (int nt = 0; nt < 8; nt++) {
        float4v a = {0.f, 0.f, 0.f, 0.f};
#pragma unroll
        for (int ks = 0; ks < 4; ks++)
            a = __builtin_amdgcn_mfma_f32_16x16x32_bf16(afr[ks], bp[(nt * 4 + ks) * 64 + lane], a, 0, 0, 0);
        acc[nt] = a;
    }
    // ---- epilogue in MFMA C-layout: lane (qtr=quad, l=col) holds rows qtr*4+r, col nt*16+l ----
    float dvarr[4];
    {
        float4 dv4 = *(const float4*)(disf + wbase + qtr * 4);
        dvarr[0] = dv4.x; dvarr[1] = dv4.y; dvarr[2] = dv4.z; dvarr[3] = dv4.w;
    }
#pragma unroll
    for (int r = 0; r < 4; r++) {
        int rowg = wbase + qtr * 4 + r;
        if (rowg < N) {
            float di = dvarr[r];
            float vv[8]; float sum = 0.f;
#pragma unroll
            for (int nt = 0; nt < 8; nt++) {
                unsigned xw = x1b[(size_t)rowg * 64 + nt * 8 + (l >> 1)];
                float xr = (l & 1) ? bfhi(xw) : bflo(xw);
                vv[nt] = xr + di * acc[nt][r] + b2[nt * 16 + l];
                sum += vv[nt];
            }
#pragma unroll
            for (int o = 8; o >= 1; o >>= 1) sum += __shfl_xor(sum, o, 64);
            float mu = sum * (1.f / DD);
            float ss = 0.f;
#pragma unroll
            for (int nt = 0; nt < 8; nt++) { float d = vv[nt] - mu; vv[nt] = d; ss += d * d; }
#pragma unroll
            for (int o = 8; o >= 1; o >>= 1) ss += __shfl_xor(ss, o, 64);
            float rstd = rsqrtf(ss * (1.f / DD) + 1e-5f);
#pragma unroll
            for (int nt = 0; nt < 8; nt++)
                out[(size_t)rowg * DD + nt * 16 + l] = vv[nt] * rstd * g2[nt * 16 + l] + beta2[nt * 16 + l];
        }
    }
}

extern "C" void kernel_launch(void* const* d_in, const int* in_sizes, int n_in,
                              void* d_out, int out_size, void* d_ws, size_t ws_size,
                              hipStream_t stream) {
    const int* node_ids = (const int*)d_in[0];
    const int* edge_index = (const int*)d_in[1];
    const float* emb   = (const float*)d_in[2];
    const float* W1    = (const float*)d_in[3];
    const float* b1    = (const float*)d_in[4];
    const float* W2    = (const float*)d_in[5];
    const float* b2    = (const float*)d_in[6];
    const float* g1    = (const float*)d_in[7];
    const float* beta1 = (const float*)d_in[8];
    const float* g2    = (const float*)d_in[9];
    const float* beta2 = (const float*)d_in[10];
    const int N = in_sizes[0];
    const int E = in_sizes[1] / 2;
    const int* srcp = edge_index;
    const int* dstp = edge_index + E;
    float* out = (float*)d_out;

    char* base = (char*)d_ws;
    size_t off = 0;
    auto carve = [&](size_t bytes) -> void* {
        void* p = base + off;
        off += (bytes + 255) & ~(size_t)255;
        return p;
    };
    int*      meta   = (int*)carve((size_t)(N + 17) * 4);   // cursor[N+16] + spillCnt
    int*      cursor = meta;
    int*      spillCnt = meta + N + 16;
    int*      spill_d = (int*)carve((size_t)SPILL_MAX * 4);
    int*      spill_r = (int*)carve((size_t)SPILL_MAX * 4);
    unsigned* recs   = (unsigned*)carve((size_t)N * CAP * 4);
    unsigned* embW1b = (unsigned*)carve((size_t)512 * 64 * 4);
    unsigned* x1b    = (unsigned*)carve((size_t)(N + 64) * 64 * 4);
    float*    disf   = (float*)carve((size_t)(N + 64) * 4);
    unsigned short* Wb = (unsigned short*)carve((size_t)DD * DD * 2);
    (void)ws_size; (void)n_in; (void)out_size;

    const int TB = 256;
    const int Hb = (E + 1023) / 1024;         // bucket segment blocks: 4 edges/thread

    hipMemsetAsync(meta, 0, (size_t)(N + 17) * 4, stream);
    k_init<<<136 + Hb, TB, 0, stream>>>(emb, W1, W2, embW1b, Wb,
                                        srcp, dstp, node_ids, cursor, recs,
                                        spillCnt, spill_d, spill_r, E);

    long long tn = (long long)((N + 3) / 4) * 64;   // one wave per 4 nodes
    int nodeBlocks = (int)((tn + TB - 1) / TB);
    k_node1<<<nodeBlocks, TB, 0, stream>>>(cursor, recs, node_ids, emb, embW1b,
                                           spillCnt, spill_d, spill_r,
                                           b1, g1, beta1, x1b, disf, N);
    int blocks64 = (N + 63) / 64;             // 64 nodes per 256-thread block (16/wave)
    k_node2<<<blocks64, TB, 0, stream>>>(cursor, recs, x1b, disf,
                                         spillCnt, spill_d, spill_r,
                                         b2, g2, beta2, Wb, out, N);
}

// Round 8
// 160.775 us; speedup vs baseline: 1.1102x; 1.0403x over previous
//
#include <hip/hip_runtime.h>

#define DD 128
#define CAP 32
#define SPILL_MAX 4096

typedef __attribute__((ext_vector_type(8))) short short8;
typedef __attribute__((ext_vector_type(4))) float float4v;

static __device__ __forceinline__ unsigned short f2bf(float x) {
    unsigned u = __builtin_bit_cast(unsigned, x);
    u += 0x7fffu + ((u >> 16) & 1u);   // RNE
    return (unsigned short)(u >> 16);
}
static __device__ __forceinline__ float bflo(unsigned u) {
    return __builtin_bit_cast(float, u << 16);
}
static __device__ __forceinline__ float bfhi(unsigned u) {
    return __builtin_bit_cast(float, u & 0xffff0000u);
}

// ---- fused init: [0,128) emb@W1 bf16 table; [128,136) W2 swizzle; [136,136+Hb) edge bucketing ----
__global__ __launch_bounds__(256) void k_init(const float* __restrict__ emb,
                                              const float* __restrict__ W1,
                                              const float* __restrict__ W2,
                                              unsigned* __restrict__ embW1b,
                                              unsigned short* __restrict__ Wb,
                                              const int* __restrict__ src,
                                              const int* __restrict__ dst,
                                              const int* __restrict__ node_ids,
                                              int* __restrict__ cursor,
                                              unsigned* __restrict__ recs,
                                              int* __restrict__ spillCnt,
                                              int* __restrict__ spill_d,
                                              int* __restrict__ spill_r, int E) {
    int blk = blockIdx.x;
    if (blk < 128) {
        int w = threadIdx.x >> 6;
        int t = threadIdx.x & 63;
        int p = blk * 4 + w;
        int c0 = t * 2, c1 = t * 2 + 1;
        float s0 = 0.f, s1 = 0.f;
#pragma unroll 8
        for (int k = 0; k < DD; k++) {
            float e = emb[p * DD + k];
            s0 += e * W1[k * DD + c0];
            s1 += e * W1[k * DD + c1];
        }
        embW1b[p * 64 + t] = (unsigned)f2bf(s0) | ((unsigned)f2bf(s1) << 16);
    } else if (blk < 136) {
        int t = (blk - 128) * 256 + threadIdx.x;   // 0..2047: (nt, ks, lane)
        int nt = t >> 8, ks = (t >> 6) & 3, lane = t & 63;
        int n = nt * 16 + (lane & 15);
        int kbase = ks * 32 + (lane >> 4) * 8;
        unsigned short* o = Wb + (size_t)t * 8;
#pragma unroll
        for (int j = 0; j < 8; j++)
            o[j] = f2bf(W2[(kbase + j) * DD + n]);
    } else {
        int base = ((blk - 136) * 256 + threadIdx.x) * 4;
        if (base >= E) return;
#pragma unroll
        for (int u = 0; u < 4; u++) {
            int e = base + u;
            if (e >= E) break;
            int s = src[e], d = dst[e];
            unsigned rec = (unsigned)s | ((unsigned)node_ids[s] << 16);
            int pos = atomicAdd(&cursor[d], 1);
            if (pos < CAP) {
                recs[(size_t)d * CAP + pos] = rec;
            } else {
                int sp = atomicAdd(spillCnt, 1);
                if (sp < SPILL_MAX) { spill_d[sp] = d; spill_r[sp] = (int)rec; }
            }
        }
    }
}

// ---- layer 1: aggregation (depth-8 pipelined loads) + LN -> x1b (bf16) + disf ----
__global__ __launch_bounds__(256, 4) void k_node1(const int* __restrict__ cursor,
                                               const unsigned* __restrict__ recs,
                                               const int* __restrict__ node_ids,
                                               const float* __restrict__ emb,
                                               const unsigned* __restrict__ embW1b,
                                               const int* __restrict__ spillCnt,
                                               const int* __restrict__ spill_d,
                                               const int* __restrict__ spill_r,
                                               const float* __restrict__ b1,
                                               const float* __restrict__ g1,
                                               const float* __restrict__ beta1,
                                               unsigned* __restrict__ x1b,
                                               float* __restrict__ disf, int N) {
    int gid = blockIdx.x * blockDim.x + threadIdx.x;
    int wave = gid >> 6;
    int lane = threadIdx.x & 63;
    int qtr = lane >> 4;
    int l = lane & 15;
    int qbase = lane & 48;
    int i = wave * 4 + qtr;
    if (i >= N) return;
    int dg = cursor[i];
    int dgc = (dg < CAP) ? dg : CAP;
    unsigned rv0 = recs[(size_t)i * CAP + l];
    unsigned rv1 = recs[(size_t)i * CAP + 16 + l];
    int c = l * 8;
    float a0 = 0.f, a1 = 0.f, a2 = 0.f, a3 = 0.f, a4 = 0.f, a5 = 0.f, a6 = 0.f, a7 = 0.f;
    for (int j0 = 0; j0 < dgc; j0 += 8) {
        unsigned rvs = (j0 < 16) ? rv0 : rv1;
        const uint4* ap[8]; const int* cp[8]; float nn[8];
#pragma unroll
        for (int q = 0; q < 8; q++) {
            int e = j0 + q;
            int ec = (e < dgc) ? e : (dgc - 1);
            unsigned rec = __shfl(rvs, qbase + (ec & 15), 64);
            nn[q] = (e < dgc) ? 1.f : 0.f;
            ap[q] = (const uint4*)(embW1b + ((rec >> 16) & 511u) * 64 + l * 4);
            cp[q] = cursor + (rec & 0xFFFFu);
        }
        uint4 buf[8]; int cb[8];
#pragma unroll
        for (int q = 0; q < 8; q++) { buf[q] = *ap[q]; cb[q] = *cp[q]; }
#pragma unroll
        for (int q = 0; q < 8; q++) {
            float n = rsqrtf((float)cb[q] + 1.f) * nn[q];
            uint4 a = buf[q];
            a0 += bflo(a.x) * n; a1 += bfhi(a.x) * n;
            a2 += bflo(a.y) * n; a3 += bfhi(a.y) * n;
            a4 += bflo(a.z) * n; a5 += bfhi(a.z) * n;
            a6 += bflo(a.w) * n; a7 += bfhi(a.w) * n;
        }
    }
    if (dg > CAP) {   // rare spill path
        int sc = *spillCnt; if (sc > SPILL_MAX) sc = SPILL_MAX;
        for (int j = 0; j < sc; j++) {
            if (spill_d[j] == i) {
                unsigned rec = (unsigned)spill_r[j];
                int s = rec & 0xFFFFu;
                float n = rsqrtf((float)cursor[s] + 1.0f);
                uint4 a = *(const uint4*)(embW1b + ((rec >> 16) & 511u) * 64 + l * 4);
                a0 += bflo(a.x) * n; a1 += bfhi(a.x) * n;
                a2 += bflo(a.y) * n; a3 += bfhi(a.y) * n;
                a4 += bflo(a.z) * n; a5 += bfhi(a.z) * n;
                a6 += bflo(a.w) * n; a7 += bfhi(a.w) * n;
            }
        }
    }
    float di = rsqrtf((float)dg + 1.0f);
    int pid = node_ids[i];
    float4 ev0 = *(const float4*)(emb + (size_t)pid * DD + c);
    float4 ev1 = *(const float4*)(emb + (size_t)pid * DD + c + 4);
    uint4 hw = *(const uint4*)(embW1b + pid * 64 + l * 4);
    float4 bb0 = *(const float4*)(b1 + c);
    float4 bb1 = *(const float4*)(b1 + c + 4);
    float v0 = ev0.x + di * (a0 + di * bflo(hw.x)) + bb0.x;
    float v1 = ev0.y + di * (a1 + di * bfhi(hw.x)) + bb0.y;
    float v2 = ev0.z + di * (a2 + di * bflo(hw.y)) + bb0.z;
    float v3 = ev0.w + di * (a3 + di * bfhi(hw.y)) + bb0.w;
    float v4 = ev1.x + di * (a4 + di * bflo(hw.z)) + bb1.x;
    float v5 = ev1.y + di * (a5 + di * bfhi(hw.z)) + bb1.y;
    float v6 = ev1.z + di * (a6 + di * bflo(hw.w)) + bb1.z;
    float v7 = ev1.w + di * (a7 + di * bfhi(hw.w)) + bb1.w;
    float sum = v0 + v1 + v2 + v3 + v4 + v5 + v6 + v7;
#pragma unroll
    for (int o = 8; o >= 1; o >>= 1) sum += __shfl_xor(sum, o, 64);
    float mu = sum * (1.f / DD);
    float d0 = v0 - mu, d1 = v1 - mu, d2 = v2 - mu, d3 = v3 - mu;
    float d4 = v4 - mu, d5 = v5 - mu, d6 = v6 - mu, d7 = v7 - mu;
    float ss = d0 * d0 + d1 * d1 + d2 * d2 + d3 * d3 + d4 * d4 + d5 * d5 + d6 * d6 + d7 * d7;
#pragma unroll
    for (int o = 8; o >= 1; o >>= 1) ss += __shfl_xor(ss, o, 64);
    float r = rsqrtf(ss * (1.f / DD) + 1e-5f);
    float4 gg0 = *(const float4*)(g1 + c);
    float4 gg1 = *(const float4*)(g1 + c + 4);
    float4 be0 = *(const float4*)(beta1 + c);
    float4 be1 = *(const float4*)(beta1 + c + 4);
    float o0 = d0 * r * gg0.x + be0.x;
    float o1 = d1 * r * gg0.y + be0.y;
    float o2 = d2 * r * gg0.z + be0.z;
    float o3 = d3 * r * gg0.w + be0.w;
    float o4 = d4 * r * gg1.x + be1.x;
    float o5 = d5 * r * gg1.y + be1.y;
    float o6 = d6 * r * gg1.z + be1.z;
    float o7 = d7 * r * gg1.w + be1.w;
    uint4 pk;
    pk.x = (unsigned)f2bf(o0) | ((unsigned)f2bf(o1) << 16);
    pk.y = (unsigned)f2bf(o2) | ((unsigned)f2bf(o3) << 16);
    pk.z = (unsigned)f2bf(o4) | ((unsigned)f2bf(o5) << 16);
    pk.w = (unsigned)f2bf(o6) | ((unsigned)f2bf(o7) << 16);
    *(uint4*)(x1b + (size_t)i * 64 + l * 4) = pk;
    if (l == 0) disf[i] = di;
}

// ---- layer 2: 4 nodes/WAVE (one per quarter), 16 nodes/block -> 3125 blocks,
//      occupancy-capped at 32 waves/CU (2.6x more resident waves than 16/wave).
//      gather z -> block tileA -> barrier -> block GEMM (wave wv: col-tiles 2wv,2wv+1)
//      -> tileH -> barrier -> per-thread LN epilogue (self-x1/di kept in regs). ----
__global__ __launch_bounds__(256, 4) void k_node2(const int* __restrict__ cursor,
                                               const unsigned* __restrict__ recs,
                                               const unsigned* __restrict__ x1b,
                                               const float* __restrict__ disf,
                                               const int* __restrict__ spillCnt,
                                               const int* __restrict__ spill_d,
                                               const int* __restrict__ spill_r,
                                               const float* __restrict__ b2,
                                               const float* __restrict__ g2,
                                               const float* __restrict__ beta2,
                                               const unsigned short* __restrict__ Wb,
                                               float* __restrict__ out, int N) {
    // tileA: 16x128 bf16, row stride 68 words (272 B): conflict-free b128 pattern
    // tileH: 16x128 f32 (post-GEMM, dis-scaled), row stride 132 words
    __shared__ unsigned tileA[16 * 68];
    __shared__ float tileH[16 * 132];
    int wv = threadIdx.x >> 6;
    int lane = threadIdx.x & 63;
    int qtr = lane >> 4;
    int l = lane & 15;
    int qbase = lane & 48;
    int base16 = blockIdx.x * 16;
    int rr = wv * 4 + qtr;             // local row 0..15, one node per quarter
    int i = base16 + rr;
    int c = l * 8;
    uint4 xv = make_uint4(0, 0, 0, 0);
    float di = 0.f;
    uint4 pk = make_uint4(0, 0, 0, 0);
    if (i < N) {
        int dg = cursor[i];
        int dgc = (dg < CAP) ? dg : CAP;
        unsigned rv0 = recs[(size_t)i * CAP + l];
        unsigned rv1 = recs[(size_t)i * CAP + 16 + l];
        float a0 = 0.f, a1 = 0.f, a2 = 0.f, a3 = 0.f, a4 = 0.f, a5 = 0.f, a6 = 0.f, a7 = 0.f;
        for (int j0 = 0; j0 < dgc; j0 += 8) {
            unsigned rvs = (j0 < 16) ? rv0 : rv1;
            const uint4* ap[8]; const float* fp[8]; float nn[8];
#pragma unroll
            for (int q = 0; q < 8; q++) {
                int e = j0 + q;
                int ec = (e < dgc) ? e : (dgc - 1);
                unsigned rec = __shfl(rvs, qbase + (ec & 15), 64);
                unsigned s = rec & 0xFFFFu;
                nn[q] = (e < dgc) ? 1.f : 0.f;
                ap[q] = (const uint4*)(x1b + (size_t)s * 64 + l * 4);
                fp[q] = disf + s;
            }
            uint4 buf[8]; float fb[8];
#pragma unroll
            for (int q = 0; q < 8; q++) { buf[q] = *ap[q]; fb[q] = *fp[q]; }
#pragma unroll
            for (int q = 0; q < 8; q++) {
                float n = fb[q] * nn[q];
                uint4 a = buf[q];
                a0 += bflo(a.x) * n; a1 += bfhi(a.x) * n;
                a2 += bflo(a.y) * n; a3 += bfhi(a.y) * n;
                a4 += bflo(a.z) * n; a5 += bfhi(a.z) * n;
                a6 += bflo(a.w) * n; a7 += bfhi(a.w) * n;
            }
        }
        if (dg > CAP) {   // rare spill path
            int sc = *spillCnt; if (sc > SPILL_MAX) sc = SPILL_MAX;
            for (int j = 0; j < sc; j++) {
                if (spill_d[j] == i) {
                    unsigned s = (unsigned)spill_r[j] & 0xFFFFu;
                    float n = disf[s];
                    uint4 a = *(const uint4*)(x1b + (size_t)s * 64 + l * 4);
                    a0 += bflo(a.x) * n; a1 += bfhi(a.x) * n;
                    a2 += bflo(a.y) * n; a3 += bfhi(a.y) * n;
                    a4 += bflo(a.z) * n; a5 += bfhi(a.z) * n;
                    a6 += bflo(a.w) * n; a7 += bfhi(a.w) * n;
                }
            }
        }
        di = disf[i];
        xv = *(const uint4*)(x1b + (size_t)i * 64 + l * 4);
        float z0 = a0 + di * bflo(xv.x);
        float z1 = a1 + di * bfhi(xv.x);
        float z2 = a2 + di * bflo(xv.y);
        float z3 = a3 + di * bfhi(xv.y);
        float z4 = a4 + di * bflo(xv.z);
        float z5 = a5 + di * bfhi(xv.z);
        float z6 = a6 + di * bflo(xv.w);
        float z7 = a7 + di * bfhi(xv.w);
        pk.x = (unsigned)f2bf(z0) | ((unsigned)f2bf(z1) << 16);
        pk.y = (unsigned)f2bf(z2) | ((unsigned)f2bf(z3) << 16);
        pk.z = (unsigned)f2bf(z4) | ((unsigned)f2bf(z5) << 16);
        pk.w = (unsigned)f2bf(z6) | ((unsigned)f2bf(z7) << 16);
    }
    *(uint4*)(tileA + rr * 68 + l * 4) = pk;
    __syncthreads();
    // ---- block GEMM: wave wv computes col-tiles nt = 2*wv, 2*wv+1 over all 16 rows ----
    {
        short8 afr[4];
        const char* tb = (const char*)tileA;
#pragma unroll
        for (int ks = 0; ks < 4; ks++)
            afr[ks] = *(const short8*)(tb + l * 272 + ks * 64 + qtr * 16);
        float dr[4];
#pragma unroll
        for (int r = 0; r < 4; r++) {
            int rw = base16 + qtr * 4 + r;
            dr[r] = (rw < N) ? disf[rw] : 0.f;   // guard: no poison NaN into dead rows
        }
        const short8* bp = (const short8*)Wb;
#pragma unroll
        for (int t = 0; t < 2; t++) {
            int nt = wv * 2 + t;
            float4v acc = {0.f, 0.f, 0.f, 0.f};
#pragma unroll
            for (int ks = 0; ks < 4; ks++)
                acc = __builtin_amdgcn_mfma_f32_16x16x32_bf16(afr[ks], bp[(nt * 4 + ks) * 64 + lane], acc, 0, 0, 0);
            int col = nt * 16 + l;
#pragma unroll
            for (int r = 0; r < 4; r++)
                tileH[(qtr * 4 + r) * 132 + col] = acc[r] * dr[r];
        }
    }
    __syncthreads();
    if (i >= N) return;
    // ---- per-thread LN epilogue: row rr, cols c..c+7; self-x1 (xv) and di from regs ----
    float4 h0 = *(const float4*)(tileH + rr * 132 + c);
    float4 h1 = *(const float4*)(tileH + rr * 132 + c + 4);
    float4 bb0 = *(const float4*)(b2 + c);
    float4 bb1 = *(const float4*)(b2 + c + 4);
    float v0 = bflo(xv.x) + h0.x + bb0.x;
    float v1 = bfhi(xv.x) + h0.y + bb0.y;
    float v2 = bflo(xv.y) + h0.z + bb0.z;
    float v3 = bfhi(xv.y) + h0.w + bb0.w;
    float v4 = bflo(xv.z) + h1.x + bb1.x;
    float v5 = bfhi(xv.z) + h1.y + bb1.y;
    float v6 = bflo(xv.w) + h1.z + bb1.z;
    float v7 = bfhi(xv.w) + h1.w + bb1.w;
    float sum = v0 + v1 + v2 + v3 + v4 + v5 + v6 + v7;
#pragma unroll
    for (int o = 8; o >= 1; o >>= 1) sum += __shfl_xor(sum, o, 64);
    float mu = sum * (1.f / DD);
    float d0 = v0 - mu, d1 = v1 - mu, d2 = v2 - mu, d3 = v3 - mu;
    float d4 = v4 - mu, d5 = v5 - mu, d6 = v6 - mu, d7 = v7 - mu;
    float ss = d0 * d0 + d1 * d1 + d2 * d2 + d3 * d3 + d4 * d4 + d5 * d5 + d6 * d6 + d7 * d7;
#pragma unroll
    for (int o = 8; o >= 1; o >>= 1) ss += __shfl_xor(ss, o, 64);
    float rstd = rsqrtf(ss * (1.f / DD) + 1e-5f);
    float4 gg0 = *(const float4*)(g2 + c);
    float4 gg1 = *(const float4*)(g2 + c + 4);
    float4 be0 = *(const float4*)(beta2 + c);
    float4 be1 = *(const float4*)(beta2 + c + 4);
    float4 o0, o1;
    o0.x = d0 * rstd * gg0.x + be0.x;
    o0.y = d1 * rstd * gg0.y + be0.y;
    o0.z = d2 * rstd * gg0.z + be0.z;
    o0.w = d3 * rstd * gg0.w + be0.w;
    o1.x = d4 * rstd * gg1.x + be1.x;
    o1.y = d5 * rstd * gg1.y + be1.y;
    o1.z = d6 * rstd * gg1.z + be1.z;
    o1.w = d7 * rstd * gg1.w + be1.w;
    *(float4*)(out + (size_t)i * DD + c) = o0;
    *(float4*)(out + (size_t)i * DD + c + 4) = o1;
}

extern "C" void kernel_launch(void* const* d_in, const int* in_sizes, int n_in,
                              void* d_out, int out_size, void* d_ws, size_t ws_size,
                              hipStream_t stream) {
    const int* node_ids = (const int*)d_in[0];
    const int* edge_index = (const int*)d_in[1];
    const float* emb   = (const float*)d_in[2];
    const float* W1    = (const float*)d_in[3];
    const float* b1    = (const float*)d_in[4];
    const float* W2    = (const float*)d_in[5];
    const float* b2    = (const float*)d_in[6];
    const float* g1    = (const float*)d_in[7];
    const float* beta1 = (const float*)d_in[8];
    const float* g2    = (const float*)d_in[9];
    const float* beta2 = (const float*)d_in[10];
    const int N = in_sizes[0];
    const int E = in_sizes[1] / 2;
    const int* srcp = edge_index;
    const int* dstp = edge_index + E;
    float* out = (float*)d_out;

    char* base = (char*)d_ws;
    size_t off = 0;
    auto carve = [&](size_t bytes) -> void* {
        void* p = base + off;
        off += (bytes + 255) & ~(size_t)255;
        return p;
    };
    int*      meta   = (int*)carve((size_t)(N + 17) * 4);   // cursor[N+16] + spillCnt
    int*      cursor = meta;
    int*      spillCnt = meta + N + 16;
    int*      spill_d = (int*)carve((size_t)SPILL_MAX * 4);
    int*      spill_r = (int*)carve((size_t)SPILL_MAX * 4);
    unsigned* recs   = (unsigned*)carve((size_t)N * CAP * 4);
    unsigned* embW1b = (unsigned*)carve((size_t)512 * 64 * 4);
    unsigned* x1b    = (unsigned*)carve((size_t)(N + 64) * 64 * 4);
    float*    disf   = (float*)carve((size_t)(N + 64) * 4);
    unsigned short* Wb = (unsigned short*)carve((size_t)DD * DD * 2);
    (void)ws_size; (void)n_in; (void)out_size;

    const int TB = 256;
    const int Hb = (E + 1023) / 1024;         // bucket segment blocks: 4 edges/thread

    hipMemsetAsync(meta, 0, (size_t)(N + 17) * 4, stream);
    k_init<<<136 + Hb, TB, 0, stream>>>(emb, W1, W2, embW1b, Wb,
                                        srcp, dstp, node_ids, cursor, recs,
                                        spillCnt, spill_d, spill_r, E);

    long long tn = (long long)((N + 3) / 4) * 64;   // one wave per 4 nodes
    int nodeBlocks = (int)((tn + TB - 1) / TB);
    k_node1<<<nodeBlocks, TB, 0, stream>>>(cursor, recs, node_ids, emb, embW1b,
                                           spillCnt, spill_d, spill_r,
                                           b1, g1, beta1, x1b, disf, N);
    int blocks16 = (N + 15) / 16;             // 16 nodes per block, 4 per wave
    k_node2<<<blocks16, TB, 0, stream>>>(cursor, recs, x1b, disf,
                                         spillCnt, spill_d, spill_r,
                                         b2, g2, beta2, Wb, out, N);
}

// Round 9
// 158.493 us; speedup vs baseline: 1.1262x; 1.0144x over previous
//
#include <hip/hip_runtime.h>

#define DD 128
#define CAP 32
#define SPILL_MAX 4096

typedef __attribute__((ext_vector_type(8))) short short8;
typedef __attribute__((ext_vector_type(4))) float float4v;

static __device__ __forceinline__ unsigned short f2bf(float x) {
    unsigned u = __builtin_bit_cast(unsigned, x);
    u += 0x7fffu + ((u >> 16) & 1u);   // RNE
    return (unsigned short)(u >> 16);
}
static __device__ __forceinline__ float bflo(unsigned u) {
    return __builtin_bit_cast(float, u << 16);
}
static __device__ __forceinline__ float bfhi(unsigned u) {
    return __builtin_bit_cast(float, u & 0xffff0000u);
}

// ---- fused init: [0,128) emb@W1 bf16 table; [128,136) W2 swizzle; [136,136+Hb) edge bucketing ----
__global__ __launch_bounds__(256) void k_init(const float* __restrict__ emb,
                                              const float* __restrict__ W1,
                                              const float* __restrict__ W2,
                                              unsigned* __restrict__ embW1b,
                                              unsigned short* __restrict__ Wb,
                                              const int* __restrict__ src,
                                              const int* __restrict__ dst,
                                              const int* __restrict__ node_ids,
                                              int* __restrict__ cursor,
                                              unsigned* __restrict__ recs,
                                              int* __restrict__ spillCnt,
                                              int* __restrict__ spill_d,
                                              int* __restrict__ spill_r, int E) {
    int blk = blockIdx.x;
    if (blk < 128) {
        int w = threadIdx.x >> 6;
        int t = threadIdx.x & 63;
        int p = blk * 4 + w;
        int c0 = t * 2, c1 = t * 2 + 1;
        float s0 = 0.f, s1 = 0.f;
#pragma unroll 8
        for (int k = 0; k < DD; k++) {
            float e = emb[p * DD + k];
            s0 += e * W1[k * DD + c0];
            s1 += e * W1[k * DD + c1];
        }
        embW1b[p * 64 + t] = (unsigned)f2bf(s0) | ((unsigned)f2bf(s1) << 16);
    } else if (blk < 136) {
        int t = (blk - 128) * 256 + threadIdx.x;   // 0..2047: (nt, ks, lane)
        int nt = t >> 8, ks = (t >> 6) & 3, lane = t & 63;
        int n = nt * 16 + (lane & 15);
        int kbase = ks * 32 + (lane >> 4) * 8;
        unsigned short* o = Wb + (size_t)t * 8;
#pragma unroll
        for (int j = 0; j < 8; j++)
            o[j] = f2bf(W2[(kbase + j) * DD + n]);
    } else {
        int base = ((blk - 136) * 256 + threadIdx.x) * 4;
        if (base >= E) return;
#pragma unroll
        for (int u = 0; u < 4; u++) {
            int e = base + u;
            if (e >= E) break;
            int s = src[e], d = dst[e];
            unsigned rec = (unsigned)s | ((unsigned)node_ids[s] << 16);
            int pos = atomicAdd(&cursor[d], 1);
            if (pos < CAP) {
                recs[(size_t)d * CAP + pos] = rec;
            } else {
                int sp = atomicAdd(spillCnt, 1);
                if (sp < SPILL_MAX) { spill_d[sp] = d; spill_r[sp] = (int)rec; }
            }
        }
    }
}

// ---- layer 1: aggregation + LN -> x1b (bf16) + disf.
//      Per-edge norm weight is preloaded ONCE by the record's owner lane and
//      shfl-broadcast with the record: halves VMEM ops in the hot loop and
//      cuts rsqrt count per edge 16x. Bit-identical numerics. ----
__global__ __launch_bounds__(256, 4) void k_node1(const int* __restrict__ cursor,
                                               const unsigned* __restrict__ recs,
                                               const int* __restrict__ node_ids,
                                               const float* __restrict__ emb,
                                               const unsigned* __restrict__ embW1b,
                                               const int* __restrict__ spillCnt,
                                               const int* __restrict__ spill_d,
                                               const int* __restrict__ spill_r,
                                               const float* __restrict__ b1,
                                               const float* __restrict__ g1,
                                               const float* __restrict__ beta1,
                                               unsigned* __restrict__ x1b,
                                               float* __restrict__ disf, int N) {
    int gid = blockIdx.x * blockDim.x + threadIdx.x;
    int wave = gid >> 6;
    int lane = threadIdx.x & 63;
    int qtr = lane >> 4;
    int l = lane & 15;
    int qbase = lane & 48;
    int i = wave * 4 + qtr;
    if (i >= N) return;
    int dg = cursor[i];
    int dgc = (dg < CAP) ? dg : CAP;
    unsigned rv0 = recs[(size_t)i * CAP + l];
    unsigned rv1 = recs[(size_t)i * CAP + 16 + l];
    // owner-lane preload of edge weights (guarded: poisoned slots -> 0)
    int s0c = (int)(rv0 & 0xFFFFu); s0c = (s0c < N) ? s0c : 0;
    int s1c = (int)(rv1 & 0xFFFFu); s1c = (s1c < N) ? s1c : 0;
    float n0 = (l < dgc) ? rsqrtf((float)cursor[s0c] + 1.f) : 0.f;
    float n1 = (16 + l < dgc) ? rsqrtf((float)cursor[s1c] + 1.f) : 0.f;
    int c = l * 8;
    float a0 = 0.f, a1 = 0.f, a2 = 0.f, a3 = 0.f, a4 = 0.f, a5 = 0.f, a6 = 0.f, a7 = 0.f;
    for (int j0 = 0; j0 < dgc; j0 += 8) {
        bool hi = (j0 >= 16);
        unsigned rvs = hi ? rv1 : rv0;
        float ns = hi ? n1 : n0;
        const uint4* ap[8]; float nw[8];
#pragma unroll
        for (int q = 0; q < 8; q++) {
            int e = j0 + q;
            int ec = (e < dgc) ? e : (dgc - 1);
            int idx = qbase + (ec & 15);
            unsigned rec = __shfl(rvs, idx, 64);
            float w = __shfl(ns, idx, 64);
            nw[q] = (e < dgc) ? w : 0.f;
            ap[q] = (const uint4*)(embW1b + ((rec >> 16) & 511u) * 64 + l * 4);
        }
        uint4 buf[8];
#pragma unroll
        for (int q = 0; q < 8; q++) buf[q] = *ap[q];
#pragma unroll
        for (int q = 0; q < 8; q++) {
            float n = nw[q];
            uint4 a = buf[q];
            a0 += bflo(a.x) * n; a1 += bfhi(a.x) * n;
            a2 += bflo(a.y) * n; a3 += bfhi(a.y) * n;
            a4 += bflo(a.z) * n; a5 += bfhi(a.z) * n;
            a6 += bflo(a.w) * n; a7 += bfhi(a.w) * n;
        }
    }
    if (dg > CAP) {   // rare spill path
        int sc = *spillCnt; if (sc > SPILL_MAX) sc = SPILL_MAX;
        for (int j = 0; j < sc; j++) {
            if (spill_d[j] == i) {
                unsigned rec = (unsigned)spill_r[j];
                int s = rec & 0xFFFFu;
                float n = rsqrtf((float)cursor[s] + 1.0f);
                uint4 a = *(const uint4*)(embW1b + ((rec >> 16) & 511u) * 64 + l * 4);
                a0 += bflo(a.x) * n; a1 += bfhi(a.x) * n;
                a2 += bflo(a.y) * n; a3 += bfhi(a.y) * n;
                a4 += bflo(a.z) * n; a5 += bfhi(a.z) * n;
                a6 += bflo(a.w) * n; a7 += bfhi(a.w) * n;
            }
        }
    }
    float di = rsqrtf((float)dg + 1.0f);
    int pid = node_ids[i];
    float4 ev0 = *(const float4*)(emb + (size_t)pid * DD + c);
    float4 ev1 = *(const float4*)(emb + (size_t)pid * DD + c + 4);
    uint4 hw = *(const uint4*)(embW1b + pid * 64 + l * 4);
    float4 bb0 = *(const float4*)(b1 + c);
    float4 bb1 = *(const float4*)(b1 + c + 4);
    float v0 = ev0.x + di * (a0 + di * bflo(hw.x)) + bb0.x;
    float v1 = ev0.y + di * (a1 + di * bfhi(hw.x)) + bb0.y;
    float v2 = ev0.z + di * (a2 + di * bflo(hw.y)) + bb0.z;
    float v3 = ev0.w + di * (a3 + di * bfhi(hw.y)) + bb0.w;
    float v4 = ev1.x + di * (a4 + di * bflo(hw.z)) + bb1.x;
    float v5 = ev1.y + di * (a5 + di * bfhi(hw.z)) + bb1.y;
    float v6 = ev1.z + di * (a6 + di * bflo(hw.w)) + bb1.z;
    float v7 = ev1.w + di * (a7 + di * bfhi(hw.w)) + bb1.w;
    float sum = v0 + v1 + v2 + v3 + v4 + v5 + v6 + v7;
#pragma unroll
    for (int o = 8; o >= 1; o >>= 1) sum += __shfl_xor(sum, o, 64);
    float mu = sum * (1.f / DD);
    float d0 = v0 - mu, d1 = v1 - mu, d2 = v2 - mu, d3 = v3 - mu;
    float d4 = v4 - mu, d5 = v5 - mu, d6 = v6 - mu, d7 = v7 - mu;
    float ss = d0 * d0 + d1 * d1 + d2 * d2 + d3 * d3 + d4 * d4 + d5 * d5 + d6 * d6 + d7 * d7;
#pragma unroll
    for (int o = 8; o >= 1; o >>= 1) ss += __shfl_xor(ss, o, 64);
    float r = rsqrtf(ss * (1.f / DD) + 1e-5f);
    float4 gg0 = *(const float4*)(g1 + c);
    float4 gg1 = *(const float4*)(g1 + c + 4);
    float4 be0 = *(const float4*)(beta1 + c);
    float4 be1 = *(const float4*)(beta1 + c + 4);
    float o0 = d0 * r * gg0.x + be0.x;
    float o1 = d1 * r * gg0.y + be0.y;
    float o2 = d2 * r * gg0.z + be0.z;
    float o3 = d3 * r * gg0.w + be0.w;
    float o4 = d4 * r * gg1.x + be1.x;
    float o5 = d5 * r * gg1.y + be1.y;
    float o6 = d6 * r * gg1.z + be1.z;
    float o7 = d7 * r * gg1.w + be1.w;
    uint4 pk;
    pk.x = (unsigned)f2bf(o0) | ((unsigned)f2bf(o1) << 16);
    pk.y = (unsigned)f2bf(o2) | ((unsigned)f2bf(o3) << 16);
    pk.z = (unsigned)f2bf(o4) | ((unsigned)f2bf(o5) << 16);
    pk.w = (unsigned)f2bf(o6) | ((unsigned)f2bf(o7) << 16);
    *(uint4*)(x1b + (size_t)i * 64 + l * 4) = pk;
    if (l == 0) disf[i] = di;
}

// ---- layer 2: 4 nodes/WAVE, 16 nodes/block; owner-lane preload of disf weight,
//      shfl-broadcast with the record (halves hot-loop VMEM ops). Block GEMM +
//      LN epilogue as R8. ----
__global__ __launch_bounds__(256, 4) void k_node2(const int* __restrict__ cursor,
                                               const unsigned* __restrict__ recs,
                                               const unsigned* __restrict__ x1b,
                                               const float* __restrict__ disf,
                                               const int* __restrict__ spillCnt,
                                               const int* __restrict__ spill_d,
                                               const int* __restrict__ spill_r,
                                               const float* __restrict__ b2,
                                               const float* __restrict__ g2,
                                               const float* __restrict__ beta2,
                                               const unsigned short* __restrict__ Wb,
                                               float* __restrict__ out, int N) {
    // tileA: 16x128 bf16, row stride 68 words (272 B): conflict-free b128 pattern
    // tileH: 16x128 f32 (post-GEMM, dis-scaled), row stride 132 words
    __shared__ unsigned tileA[16 * 68];
    __shared__ float tileH[16 * 132];
    int wv = threadIdx.x >> 6;
    int lane = threadIdx.x & 63;
    int qtr = lane >> 4;
    int l = lane & 15;
    int qbase = lane & 48;
    int base16 = blockIdx.x * 16;
    int rr = wv * 4 + qtr;             // local row 0..15, one node per quarter
    int i = base16 + rr;
    int c = l * 8;
    uint4 xv = make_uint4(0, 0, 0, 0);
    float di = 0.f;
    uint4 pk = make_uint4(0, 0, 0, 0);
    if (i < N) {
        int dg = cursor[i];
        int dgc = (dg < CAP) ? dg : CAP;
        unsigned rv0 = recs[(size_t)i * CAP + l];
        unsigned rv1 = recs[(size_t)i * CAP + 16 + l];
        // owner-lane preload of edge weights (guarded: poisoned slots -> 0)
        int s0c = (int)(rv0 & 0xFFFFu); s0c = (s0c < N) ? s0c : 0;
        int s1c = (int)(rv1 & 0xFFFFu); s1c = (s1c < N) ? s1c : 0;
        float f0 = (l < dgc) ? disf[s0c] : 0.f;
        float f1 = (16 + l < dgc) ? disf[s1c] : 0.f;
        float a0 = 0.f, a1 = 0.f, a2 = 0.f, a3 = 0.f, a4 = 0.f, a5 = 0.f, a6 = 0.f, a7 = 0.f;
        for (int j0 = 0; j0 < dgc; j0 += 8) {
            bool hi = (j0 >= 16);
            unsigned rvs = hi ? rv1 : rv0;
            float fs = hi ? f1 : f0;
            const uint4* ap[8]; float nw[8];
#pragma unroll
            for (int q = 0; q < 8; q++) {
                int e = j0 + q;
                int ec = (e < dgc) ? e : (dgc - 1);
                int idx = qbase + (ec & 15);
                unsigned rec = __shfl(rvs, idx, 64);
                float w = __shfl(fs, idx, 64);
                nw[q] = (e < dgc) ? w : 0.f;
                ap[q] = (const uint4*)(x1b + (size_t)(rec & 0xFFFFu) * 64 + l * 4);
            }
            uint4 buf[8];
#pragma unroll
            for (int q = 0; q < 8; q++) buf[q] = *ap[q];
#pragma unroll
            for (int q = 0; q < 8; q++) {
                float n = nw[q];
                uint4 a = buf[q];
                a0 += bflo(a.x) * n; a1 += bfhi(a.x) * n;
                a2 += bflo(a.y) * n; a3 += bfhi(a.y) * n;
                a4 += bflo(a.z) * n; a5 += bfhi(a.z) * n;
                a6 += bflo(a.w) * n; a7 += bfhi(a.w) * n;
            }
        }
        if (dg > CAP) {   // rare spill path
            int sc = *spillCnt; if (sc > SPILL_MAX) sc = SPILL_MAX;
            for (int j = 0; j < sc; j++) {
                if (spill_d[j] == i) {
                    unsigned s = (unsigned)spill_r[j] & 0xFFFFu;
                    float n = disf[s];
                    uint4 a = *(const uint4*)(x1b + (size_t)s * 64 + l * 4);
                    a0 += bflo(a.x) * n; a1 += bfhi(a.x) * n;
                    a2 += bflo(a.y) * n; a3 += bfhi(a.y) * n;
                    a4 += bflo(a.z) * n; a5 += bfhi(a.z) * n;
                    a6 += bflo(a.w) * n; a7 += bfhi(a.w) * n;
                }
            }
        }
        di = disf[i];
        xv = *(const uint4*)(x1b + (size_t)i * 64 + l * 4);
        float z0 = a0 + di * bflo(xv.x);
        float z1 = a1 + di * bfhi(xv.x);
        float z2 = a2 + di * bflo(xv.y);
        float z3 = a3 + di * bfhi(xv.y);
        float z4 = a4 + di * bflo(xv.z);
        float z5 = a5 + di * bfhi(xv.z);
        float z6 = a6 + di * bflo(xv.w);
        float z7 = a7 + di * bfhi(xv.w);
        pk.x = (unsigned)f2bf(z0) | ((unsigned)f2bf(z1) << 16);
        pk.y = (unsigned)f2bf(z2) | ((unsigned)f2bf(z3) << 16);
        pk.z = (unsigned)f2bf(z4) | ((unsigned)f2bf(z5) << 16);
        pk.w = (unsigned)f2bf(z6) | ((unsigned)f2bf(z7) << 16);
    }
    *(uint4*)(tileA + rr * 68 + l * 4) = pk;
    __syncthreads();
    // ---- block GEMM: wave wv computes col-tiles nt = 2*wv, 2*wv+1 over all 16 rows ----
    {
        short8 afr[4];
        const char* tb = (const char*)tileA;
#pragma unroll
        for (int ks = 0; ks < 4; ks++)
            afr[ks] = *(const short8*)(tb + l * 272 + ks * 64 + qtr * 16);
        float dr[4];
#pragma unroll
        for (int r = 0; r < 4; r++) {
            int rw = base16 + qtr * 4 + r;
            dr[r] = (rw < N) ? disf[rw] : 0.f;   // guard: no poison NaN into dead rows
        }
        const short8* bp = (const short8*)Wb;
#pragma unroll
        for (int t = 0; t < 2; t++) {
            int nt = wv * 2 + t;
            float4v acc = {0.f, 0.f, 0.f, 0.f};
#pragma unroll
            for (int ks = 0; ks < 4; ks++)
                acc = __builtin_amdgcn_mfma_f32_16x16x32_bf16(afr[ks], bp[(nt * 4 + ks) * 64 + lane], acc, 0, 0, 0);
            int col = nt * 16 + l;
#pragma unroll
            for (int r = 0; r < 4; r++)
                tileH[(qtr * 4 + r) * 132 + col] = acc[r] * dr[r];
        }
    }
    __syncthreads();
    if (i >= N) return;
    // ---- per-thread LN epilogue: row rr, cols c..c+7; self-x1 (xv) and di from regs ----
    float4 h0 = *(const float4*)(tileH + rr * 132 + c);
    float4 h1 = *(const float4*)(tileH + rr * 132 + c + 4);
    float4 bb0 = *(const float4*)(b2 + c);
    float4 bb1 = *(const float4*)(b2 + c + 4);
    float v0 = bflo(xv.x) + h0.x + bb0.x;
    float v1 = bfhi(xv.x) + h0.y + bb0.y;
    float v2 = bflo(xv.y) + h0.z + bb0.z;
    float v3 = bfhi(xv.y) + h0.w + bb0.w;
    float v4 = bflo(xv.z) + h1.x + bb1.x;
    float v5 = bfhi(xv.z) + h1.y + bb1.y;
    float v6 = bflo(xv.w) + h1.z + bb1.z;
    float v7 = bfhi(xv.w) + h1.w + bb1.w;
    float sum = v0 + v1 + v2 + v3 + v4 + v5 + v6 + v7;
#pragma unroll
    for (int o = 8; o >= 1; o >>= 1) sum += __shfl_xor(sum, o, 64);
    float mu = sum * (1.f / DD);
    float d0 = v0 - mu, d1 = v1 - mu, d2 = v2 - mu, d3 = v3 - mu;
    float d4 = v4 - mu, d5 = v5 - mu, d6 = v6 - mu, d7 = v7 - mu;
    float ss = d0 * d0 + d1 * d1 + d2 * d2 + d3 * d3 + d4 * d4 + d5 * d5 + d6 * d6 + d7 * d7;
#pragma unroll
    for (int o = 8; o >= 1; o >>= 1) ss += __shfl_xor(ss, o, 64);
    float rstd = rsqrtf(ss * (1.f / DD) + 1e-5f);
    float4 gg0 = *(const float4*)(g2 + c);
    float4 gg1 = *(const float4*)(g2 + c + 4);
    float4 be0 = *(const float4*)(beta2 + c);
    float4 be1 = *(const float4*)(beta2 + c + 4);
    float4 o0, o1;
    o0.x = d0 * rstd * gg0.x + be0.x;
    o0.y = d1 * rstd * gg0.y + be0.y;
    o0.z = d2 * rstd * gg0.z + be0.z;
    o0.w = d3 * rstd * gg0.w + be0.w;
    o1.x = d4 * rstd * gg1.x + be1.x;
    o1.y = d5 * rstd * gg1.y + be1.y;
    o1.z = d6 * rstd * gg1.z + be1.z;
    o1.w = d7 * rstd * gg1.w + be1.w;
    *(float4*)(out + (size_t)i * DD + c) = o0;
    *(float4*)(out + (size_t)i * DD + c + 4) = o1;
}

extern "C" void kernel_launch(void* const* d_in, const int* in_sizes, int n_in,
                              void* d_out, int out_size, void* d_ws, size_t ws_size,
                              hipStream_t stream) {
    const int* node_ids = (const int*)d_in[0];
    const int* edge_index = (const int*)d_in[1];
    const float* emb   = (const float*)d_in[2];
    const float* W1    = (const float*)d_in[3];
    const float* b1    = (const float*)d_in[4];
    const float* W2    = (const float*)d_in[5];
    const float* b2    = (const float*)d_in[6];
    const float* g1    = (const float*)d_in[7];
    const float* beta1 = (const float*)d_in[8];
    const float* g2    = (const float*)d_in[9];
    const float* beta2 = (const float*)d_in[10];
    const int N = in_sizes[0];
    const int E = in_sizes[1] / 2;
    const int* srcp = edge_index;
    const int* dstp = edge_index + E;
    float* out = (float*)d_out;

    char* base = (char*)d_ws;
    size_t off = 0;
    auto carve = [&](size_t bytes) -> void* {
        void* p = base + off;
        off += (bytes + 255) & ~(size_t)255;
        return p;
    };
    int*      meta   = (int*)carve((size_t)(N + 17) * 4);   // cursor[N+16] + spillCnt
    int*      cursor = meta;
    int*      spillCnt = meta + N + 16;
    int*      spill_d = (int*)carve((size_t)SPILL_MAX * 4);
    int*      spill_r = (int*)carve((size_t)SPILL_MAX * 4);
    unsigned* recs   = (unsigned*)carve((size_t)N * CAP * 4);
    unsigned* embW1b = (unsigned*)carve((size_t)512 * 64 * 4);
    unsigned* x1b    = (unsigned*)carve((size_t)(N + 64) * 64 * 4);
    float*    disf   = (float*)carve((size_t)(N + 64) * 4);
    unsigned short* Wb = (unsigned short*)carve((size_t)DD * DD * 2);
    (void)ws_size; (void)n_in; (void)out_size;

    const int TB = 256;
    const int Hb = (E + 1023) / 1024;         // bucket segment blocks: 4 edges/thread

    hipMemsetAsync(meta, 0, (size_t)(N + 17) * 4, stream);
    k_init<<<136 + Hb, TB, 0, stream>>>(emb, W1, W2, embW1b, Wb,
                                        srcp, dstp, node_ids, cursor, recs,
                                        spillCnt, spill_d, spill_r, E);

    long long tn = (long long)((N + 3) / 4) * 64;   // one wave per 4 nodes
    int nodeBlocks = (int)((tn + TB - 1) / TB);
    k_node1<<<nodeBlocks, TB, 0, stream>>>(cursor, recs, node_ids, emb, embW1b,
                                           spillCnt, spill_d, spill_r,
                                           b1, g1, beta1, x1b, disf, N);
    int blocks16 = (N + 15) / 16;             // 16 nodes per block, 4 per wave
    k_node2<<<blocks16, TB, 0, stream>>>(cursor, recs, x1b, disf,
                                         spillCnt, spill_d, spill_r,
                                         b2, g2, beta2, Wb, out, N);
}